// Round 8
// baseline (72.997 us; speedup 1.0000x reference)
//
#include <hip/hip_runtime.h>
#include <math.h>

#define NB 2
#define NTOK 16384
#define CDIM 64
#define WIMG 128
#define NKV 256
#define NHEAD 8
#define HDIM 8
#define KTOT 4096
#define KSPLIT 16
#define RTOKS 512  // NB*NKV reduced tokens

typedef unsigned short u16;
typedef __attribute__((ext_vector_type(8))) short bf16x8;
typedef __attribute__((ext_vector_type(4))) unsigned int u32x4;
typedef __attribute__((ext_vector_type(2))) unsigned int u32x2;
typedef __attribute__((ext_vector_type(16))) float f32x16;

// softmax scale folded with log2(e), applied to K before bf16 quantization
constexpr float KSCALE = 0.35355339059327373f * 1.4426950408889634f;

__device__ __forceinline__ u16 f2bf(float f) {   // RNE f32->bf16
  unsigned u = __builtin_bit_cast(unsigned, f);
  return (u16)((u + 0x7FFFu + ((u >> 16) & 1u)) >> 16);
}

__device__ __forceinline__ f32x16 mfma32x16(bf16x8 a, bf16x8 b, f32x16 c) {
  return __builtin_amdgcn_mfma_f32_32x32x16_bf16(a, b, c, 0, 0, 0);
}

__device__ __forceinline__ void pl32swap(unsigned &a, unsigned &b) {
  u32x2 r = __builtin_amdgcn_permlane32_swap(a, b, false, false);
  a = r[0]; b = r[1];
}

__device__ __forceinline__ float fexp2(float x) {
  float r;
  asm("v_exp_f32 %0, %1" : "=v"(r) : "v"(x));
  return r;
}

__device__ __forceinline__ float wave_reduce_sum64(float v) {
  #pragma unroll
  for (int off = 32; off > 0; off >>= 1) v += __shfl_xor(v, off, 64);
  return v;
}

// ---------------- K0: transpose conv weight [O][I][8][8] -> W2T[kk][o], kk = pos*64+i
__global__ __launch_bounds__(256) void k0_transpose_w(const float* __restrict__ srw,
                                                      float* __restrict__ w2t) {
  int idx = blockIdx.x * 256 + threadIdx.x;   // 262144 total
  int kk = idx >> 6;
  int o  = idx & 63;
  int pos = kk >> 6;
  int i   = kk & 63;
  w2t[idx] = srw[(o << 12) + (i << 6) + pos];
}

// ---------------- K1: conv as K-split GEMM. grid (16 token tiles, 16 k-chunks)
__global__ __launch_bounds__(256) void k1_conv_partial(const float* __restrict__ x,
                                                       const float* __restrict__ w2t,
                                                       float* __restrict__ pbuf) {
  __shared__ float xs[32][68];
  __shared__ float ws[64][68];
  const int t = threadIdx.x;
  const int tile = blockIdx.x;   // 0..15
  const int kch  = blockIdx.y;   // 0..15
  const int lr = t >> 3, li0 = (t & 7) << 3;     // x: 32 rows x 64
  const int tgL = tile * 32 + lr;
  const int bL  = tgL >> 8;
  const int pL  = tgL & 255;
  const int phL = pL >> 4, pwL = pL & 15;
  const int wr = t >> 2, wo0 = (t & 3) << 4;     // w: 64 rows x 64
  const int tokl = t >> 3;
  const int ob   = (t & 7) << 3;
  float acc[8];
  #pragma unroll
  for (int j = 0; j < 8; ++j) acc[j] = 0.f;

  for (int sc = 0; sc < 4; ++sc) {
    const int k0  = kch * 256 + sc * 64;   // 64-aligned chunk == one conv tap position
    const int pos = k0 >> 6;
    const int kh = pos >> 3, kw = pos & 7;
    const int nrow = (phL * 8 + kh) * WIMG + (pwL * 8 + kw);
    const float* xsrc = x + ((size_t)bL * NTOK + nrow) * CDIM + li0;
    float4 a0 = *(const float4*)(xsrc);
    float4 a1 = *(const float4*)(xsrc + 4);
    const float* wsrc = w2t + (size_t)(k0 + wr) * 64 + wo0;
    float4 b0 = *(const float4*)(wsrc);
    float4 b1 = *(const float4*)(wsrc + 4);
    float4 b2 = *(const float4*)(wsrc + 8);
    float4 b3 = *(const float4*)(wsrc + 12);
    __syncthreads();
    *(float4*)&xs[lr][li0]     = a0;
    *(float4*)&xs[lr][li0 + 4] = a1;
    *(float4*)&ws[wr][wo0]      = b0;
    *(float4*)&ws[wr][wo0 + 4]  = b1;
    *(float4*)&ws[wr][wo0 + 8]  = b2;
    *(float4*)&ws[wr][wo0 + 12] = b3;
    __syncthreads();
    #pragma unroll 16
    for (int kk2 = 0; kk2 < 64; ++kk2) {
      const float xv = xs[tokl][kk2];
      #pragma unroll
      for (int j = 0; j < 8; ++j) acc[j] += xv * ws[kk2][ob + j];
    }
  }
  const int tg = tile * 32 + tokl;
  float* dst = pbuf + ((size_t)kch * RTOKS + tg) * 64 + ob;
  #pragma unroll
  for (int j = 0; j < 8; ++j) dst[j] = acc[j];
}

// ---------------- K2: reduce partials + bias + LN + KV proj -> bf16 K (scaled), bf16 V^T
__global__ __launch_bounds__(64) void k2_ln_kv(const float* __restrict__ pbuf,
                                               const float* __restrict__ srb,
                                               const float* __restrict__ lng,
                                               const float* __restrict__ lnb,
                                               const float* __restrict__ kvw,
                                               u16* __restrict__ kbuf,
                                               u16* __restrict__ vbufT) {
  __shared__ float ylds[64];
  const int tg = blockIdx.x;    // 0..511 reduced token
  const int o  = threadIdx.x;   // 0..63 channel
  float y = srb[o];
  #pragma unroll
  for (int s = 0; s < KSPLIT; ++s) y += pbuf[((size_t)s * RTOKS + tg) * 64 + o];
  const float sum   = wave_reduce_sum64(y);
  const float sumsq = wave_reduce_sum64(y * y);
  const float mu  = sum * (1.f / 64.f);
  const float var = sumsq * (1.f / 64.f) - mu * mu;
  const float rstd = rsqrtf(var + 1e-5f);
  const float yn = (y - mu) * rstd * lng[o] + lnb[o];
  ylds[o] = yn;
  __syncthreads();
  float ka = 0.f, va = 0.f;
  #pragma unroll 16
  for (int i = 0; i < 64; ++i) {
    const float yv = ylds[i];
    ka += yv * kvw[i * 128 + o];
    va += yv * kvw[i * 128 + 64 + o];
  }
  const int b = tg >> 8, p = tg & 255;
  const int h = o >> 3, d = o & 7;
  const int bh = b * NHEAD + h;
  kbuf[((size_t)bh * NKV + p) * HDIM + d] = f2bf(ka * KSCALE);
  vbufT[((size_t)bh * HDIM + d) * NKV + p] = f2bf(va);
}

// ---------------- K3: q = x @ q_w (f32 LDS GEMM), stored head-major bf16 [B][H][N][8]
__global__ __launch_bounds__(256) void k3_qproj(const float* __restrict__ x,
                                                const float* __restrict__ qw,
                                                u16* __restrict__ qbuf) {
  __shared__ float xs[64][68];
  __shared__ float wsq[64][68];
  const int t = threadIdx.x;
  const int blk = blockIdx.x;          // 0..511
  const int b = blk >> 8;
  const int tok0 = (blk & 255) * 64;
  const int lr = t >> 2, lc0 = (t & 3) << 4;
  {
    const float* src = x + ((size_t)b * NTOK + tok0 + lr) * CDIM + lc0;
    float4 v0 = *(const float4*)(src);
    float4 v1 = *(const float4*)(src + 4);
    float4 v2 = *(const float4*)(src + 8);
    float4 v3 = *(const float4*)(src + 12);
    *(float4*)&xs[lr][lc0]      = v0;
    *(float4*)&xs[lr][lc0 + 4]  = v1;
    *(float4*)&xs[lr][lc0 + 8]  = v2;
    *(float4*)&xs[lr][lc0 + 12] = v3;
    const float* wsrc = qw + lr * 64 + lc0;
    float4 w0 = *(const float4*)(wsrc);
    float4 w1 = *(const float4*)(wsrc + 4);
    float4 w2 = *(const float4*)(wsrc + 8);
    float4 w3 = *(const float4*)(wsrc + 12);
    *(float4*)&wsq[lr][lc0]      = w0;
    *(float4*)&wsq[lr][lc0 + 4]  = w1;
    *(float4*)&wsq[lr][lc0 + 8]  = w2;
    *(float4*)&wsq[lr][lc0 + 12] = w3;
  }
  __syncthreads();
  const int tok = t >> 2, cb = (t & 3) << 4;
  float acc[16];
  #pragma unroll
  for (int j = 0; j < 16; ++j) acc[j] = 0.f;
  #pragma unroll 16
  for (int c = 0; c < 64; ++c) {
    const float xv = xs[tok][c];
    #pragma unroll
    for (int j = 0; j < 16; ++j) acc[j] += xv * wsq[c][cb + j];
  }
  const int tokg = tok0 + tok;
  #pragma unroll
  for (int g = 0; g < 2; ++g) {
    const int h = (cb >> 3) + g;
    const int bh = b * NHEAD + h;
    u16* dst = qbuf + ((size_t)bh * NTOK + tokg) * HDIM;
    uint4 w;
    w.x = (unsigned)f2bf(acc[g*8+0]) | ((unsigned)f2bf(acc[g*8+1]) << 16);
    w.y = (unsigned)f2bf(acc[g*8+2]) | ((unsigned)f2bf(acc[g*8+3]) << 16);
    w.z = (unsigned)f2bf(acc[g*8+4]) | ((unsigned)f2bf(acc[g*8+5]) << 16);
    w.w = (unsigned)f2bf(acc[g*8+6]) | ((unsigned)f2bf(acc[g*8+7]) << 16);
    *(uint4*)dst = w;
  }
}

// ---------------- K4 v5: round-4 verified MFMA attention, register-dieted.
// One 32-query tile per wave (grid 2048x256 = 8192 waves -> occupancy not
// grid-capped). kf loaded per-kblk, vf per-(kblk,jj) from L2 (K/V 32 KB total).
// Arithmetic sequence identical to round 4 (bit-identical output).
__global__ __launch_bounds__(256) void k4_attn_mfma(const u16* __restrict__ qbuf,
                                                    const u16* __restrict__ kbuf,
                                                    const u16* __restrict__ vbufT,
                                                    float* __restrict__ abuf) {
  const int t = threadIdx.x;
  const int lane = t & 63;
  const int w = blockIdx.x * 4 + (t >> 6);   // global wave id, 0..8191
  const int bh = w >> 9;                     // 16 (b,h) pairs, 512 waves each
  const int qt = (w & 511) * 32;             // this wave's query tile
  const int lo = lane & 31;
  const int hi = lane >> 5;

  const u16* kb = kbuf + (size_t)bh * NKV * HDIM;
  const u16* vb = vbufT + (size_t)bh * HDIM * NKV;

  // Q^T fragment: B[k][n=query]; hi=0 lanes hold k=0..7 = Q row; hi=1 zero pad
  bf16x8 qf = {0, 0, 0, 0, 0, 0, 0, 0};
  if (hi == 0)
    qf = *(const bf16x8*)(qbuf + ((size_t)bh * NTOK + qt + lo) * HDIM);

  f32x16 oacc;
  #pragma unroll
  for (int i = 0; i < 16; ++i) oacc[i] = 0.f;
  float den = 0.f;

  #pragma unroll
  for (int kblk = 0; kblk < 8; ++kblk) {
    // K fragment: A[m=key][k]; hi=0 lanes hold k=0..7 = K row; hi=1 zero pad
    bf16x8 kf = {0, 0, 0, 0, 0, 0, 0, 0};
    if (hi == 0) kf = *(const bf16x8*)(kb + (kblk * 32 + lo) * HDIM);

    f32x16 s;
    #pragma unroll
    for (int i = 0; i < 16; ++i) s[i] = 0.f;
    s = mfma32x16(kf, qf, s);   // S^T tile: rows=keys kblk*32+.., cols=queries

    float p[16];
    #pragma unroll
    for (int r = 0; r < 16; ++r) p[r] = fexp2(s[r]);
    #pragma unroll
    for (int r = 0; r < 16; ++r) den += p[r];

    unsigned pk01[4], pk23[4];
    #pragma unroll
    for (int q = 0; q < 4; ++q) {
      asm("v_cvt_pk_bf16_f32 %0, %1, %2" : "=v"(pk01[q]) : "v"(p[4*q+0]), "v"(p[4*q+1]));
      asm("v_cvt_pk_bf16_f32 %0, %1, %2" : "=v"(pk23[q]) : "v"(p[4*q+2]), "v"(p[4*q+3]));
    }
    #pragma unroll
    for (int jj = 0; jj < 2; ++jj) {
      unsigned a0 = pk01[2*jj], b0 = pk01[2*jj+1];
      unsigned a1 = pk23[2*jj], b1 = pk23[2*jj+1];
      pl32swap(a0, b0);
      pl32swap(a1, b1);
      u32x4 wv; wv[0] = a0; wv[1] = a1; wv[2] = b0; wv[3] = b1;
      bf16x8 pfrag = __builtin_bit_cast(bf16x8, wv);
      // V^T fragment: A[m=d][k=key]; lane supplies k = 8*hi+i; rows d>=8 zero
      bf16x8 vf = {0, 0, 0, 0, 0, 0, 0, 0};
      if (lo < 8)
        vf = *(const bf16x8*)(vb + lo * NKV + kblk * 32 + jj * 16 + hi * 8);
      oacc = mfma32x16(vf, pfrag, oacc);
    }
  }

  // epilogue: O^T col=query=lo; regs0-3 = d(0..3|4..7 by hi); den: this lane's
  // 16 S^T rows + partner's 16.
  den += __shfl_xor(den, 32, 64);
  const float r = 1.0f / den;
  float4 o;
  o.x = oacc[0] * r; o.y = oacc[1] * r; o.z = oacc[2] * r; o.w = oacc[3] * r;
  *(float4*)(abuf + ((size_t)bh * NTOK + qt + lo) * HDIM + hi * 4) = o;
}

// ---------------- K5: output projection + bias (round-4 verified verbatim)
__global__ __launch_bounds__(256) void k5_proj(const float* __restrict__ abuf,
                                               const float* __restrict__ pw,
                                               const float* __restrict__ pb,
                                               float* __restrict__ out) {
  __shared__ float as_[64][68];
  __shared__ float wsp[64][68];
  const int t = threadIdx.x;
  const int blk = blockIdx.x;  // 0..511
  const int b = blk >> 8;
  const int tok0 = (blk & 255) * 64;
  {
    const int h = t >> 5;
    const int rem = (t & 31) << 4;
    const int tokL = rem >> 3;
    const float* src = abuf + (((size_t)b * NHEAD + h) * NTOK + tok0 + tokL) * HDIM;
    float4 v0 = *(const float4*)(src);
    float4 v1 = *(const float4*)(src + 4);
    float4 v2 = *(const float4*)(src + 8);
    float4 v3 = *(const float4*)(src + 12);
    *(float4*)&as_[tokL][h * 8]         = v0;
    *(float4*)&as_[tokL][h * 8 + 4]     = v1;
    *(float4*)&as_[tokL + 1][h * 8]     = v2;
    *(float4*)&as_[tokL + 1][h * 8 + 4] = v3;
    const int wr = t >> 2, wc0 = (t & 3) << 4;
    const float* wsrc = pw + wr * 64 + wc0;
    float4 w0 = *(const float4*)(wsrc);
    float4 w1 = *(const float4*)(wsrc + 4);
    float4 w2 = *(const float4*)(wsrc + 8);
    float4 w3 = *(const float4*)(wsrc + 12);
    *(float4*)&wsp[wr][wc0]      = w0;
    *(float4*)&wsp[wr][wc0 + 4]  = w1;
    *(float4*)&wsp[wr][wc0 + 8]  = w2;
    *(float4*)&wsp[wr][wc0 + 12] = w3;
  }
  __syncthreads();
  const int tok = t >> 2, cb = (t & 3) << 4;
  float acc[16];
  #pragma unroll
  for (int j = 0; j < 16; ++j) acc[j] = 0.f;
  #pragma unroll 16
  for (int c = 0; c < 64; ++c) {
    const float xv = as_[tok][c];
    #pragma unroll
    for (int j = 0; j < 16; ++j) acc[j] += xv * wsp[c][cb + j];
  }
  float* dst = out + ((size_t)b * NTOK + tok0 + tok) * CDIM + cb;
  #pragma unroll
  for (int j = 0; j < 16; ++j) acc[j] += pb[cb + j];
  *(float4*)(dst)      = make_float4(acc[0], acc[1], acc[2], acc[3]);
  *(float4*)(dst + 4)  = make_float4(acc[4], acc[5], acc[6], acc[7]);
  *(float4*)(dst + 8)  = make_float4(acc[8], acc[9], acc[10], acc[11]);
  *(float4*)(dst + 12) = make_float4(acc[12], acc[13], acc[14], acc[15]);
}

extern "C" void kernel_launch(void* const* d_in, const int* in_sizes, int n_in,
                              void* d_out, int out_size, void* d_ws, size_t ws_size,
                              hipStream_t stream) {
  const float* x    = (const float*)d_in[0];
  // d_in[1], d_in[2] are H, W scalars (128, 128) — fixed by the problem
  const float* qw   = (const float*)d_in[3];
  const float* kvw  = (const float*)d_in[4];
  const float* srw  = (const float*)d_in[5];
  const float* srb  = (const float*)d_in[6];
  const float* lng  = (const float*)d_in[7];
  const float* lnb  = (const float*)d_in[8];
  const float* pw   = (const float*)d_in[9];
  const float* pb   = (const float*)d_in[10];
  float* out = (float*)d_out;
  float* ws  = (float*)d_ws;

  float* w2t   = ws;                        // 262144 floats
  float* pbuf  = ws + 262144;               // 524288 floats
  u16*   kbuf  = (u16*)(ws + 786432);       // 32768 bf16  (16384 floats)
  u16*   vbufT = (u16*)(ws + 802816);       // 32768 bf16  (16384 floats)
  u16*   qbuf  = (u16*)(ws + 819200);       // 2097152 bf16 (1048576 floats)
  float* abuf  = ws + 1867776;              // 2097152 floats

  k0_transpose_w<<<1024, 256, 0, stream>>>(srw, w2t);
  k1_conv_partial<<<dim3(16, 16), 256, 0, stream>>>(x, w2t, pbuf);
  k2_ln_kv<<<512, 64, 0, stream>>>(pbuf, srb, lng, lnb, kvw, kbuf, vbufT);
  k3_qproj<<<512, 256, 0, stream>>>(x, qw, qbuf);
  k4_attn_mfma<<<2048, 256, 0, stream>>>(qbuf, kbuf, vbufT, abuf);
  k5_proj<<<512, 256, 0, stream>>>(abuf, pw, pb, out);
}

// Round 9
// 64.342 us; speedup vs baseline: 1.1345x; 1.1345x over previous
//
#include <hip/hip_runtime.h>
#include <math.h>

#define NB 2
#define NTOK 16384
#define CDIM 64
#define WIMG 128
#define NKV 256
#define NHEAD 8
#define HDIM 8
#define RTOKS 512  // NB*NKV reduced tokens
#define NTAP 64    // 8x8 conv taps

typedef unsigned short u16;
typedef __attribute__((ext_vector_type(8))) short bf16x8;
typedef __attribute__((ext_vector_type(4))) unsigned int u32x4;
typedef __attribute__((ext_vector_type(2))) unsigned int u32x2;
typedef __attribute__((ext_vector_type(16))) float f32x16;

// softmax scale folded with log2(e), applied to K before bf16 quantization
constexpr float KSCALE = 0.35355339059327373f * 1.4426950408889634f;

__device__ __forceinline__ u16 f2bf(float f) {   // RNE f32->bf16
  unsigned u = __builtin_bit_cast(unsigned, f);
  return (u16)((u + 0x7FFFu + ((u >> 16) & 1u)) >> 16);
}

__device__ __forceinline__ f32x16 mfma32x16(bf16x8 a, bf16x8 b, f32x16 c) {
  return __builtin_amdgcn_mfma_f32_32x32x16_bf16(a, b, c, 0, 0, 0);
}

__device__ __forceinline__ void pl32swap(unsigned &a, unsigned &b) {
  u32x2 r = __builtin_amdgcn_permlane32_swap(a, b, false, false);
  a = r[0]; b = r[1];
}

__device__ __forceinline__ float fexp2(float x) {
  float r;
  asm("v_exp_f32 %0, %1" : "=v"(r) : "v"(x));
  return r;
}

// split 8 f32 into hi/lo bf16 fragments: v ~= hi + lo (hi: RNE-ish via cvt_pk)
__device__ __forceinline__ void split8(const float* v, bf16x8& hout, bf16x8& lout) {
  unsigned hw[4], lw[4];
  float hf[8], lof[8];
  #pragma unroll
  for (int q = 0; q < 4; ++q)
    asm("v_cvt_pk_bf16_f32 %0, %1, %2" : "=v"(hw[q]) : "v"(v[2*q]), "v"(v[2*q+1]));
  #pragma unroll
  for (int q = 0; q < 4; ++q) {
    hf[2*q]   = __builtin_bit_cast(float, hw[q] << 16);
    hf[2*q+1] = __builtin_bit_cast(float, hw[q] & 0xFFFF0000u);
  }
  #pragma unroll
  for (int j = 0; j < 8; ++j) lof[j] = v[j] - hf[j];
  #pragma unroll
  for (int q = 0; q < 4; ++q)
    asm("v_cvt_pk_bf16_f32 %0, %1, %2" : "=v"(lw[q]) : "v"(lof[2*q]), "v"(lof[2*q+1]));
  u32x4 H; H[0] = hw[0]; H[1] = hw[1]; H[2] = hw[2]; H[3] = hw[3];
  u32x4 L; L[0] = lw[0]; L[1] = lw[1]; L[2] = lw[2]; L[3] = lw[3];
  hout = __builtin_bit_cast(bf16x8, H);
  lout = __builtin_bit_cast(bf16x8, L);
}

__device__ __forceinline__ float wave_reduce_sum64(float v) {
  #pragma unroll
  for (int off = 32; off > 0; off >>= 1) v += __shfl_xor(v, off, 64);
  return v;
}

// ---------------- kA: conv tap-partials via split-bf16 MFMA (f32-quality).
// grid(16 token-tiles, 32 tap-pairs), block 256 = 4 waves: wave -> (tap, oc-half).
// C[m=tok32][n=oc32] accumulated over k=64 input channels; 12 mfma/wave.
__global__ __launch_bounds__(256) void kA_conv(const float* __restrict__ x,
                                               const float* __restrict__ srw,
                                               float* __restrict__ pbuf) {
  const int t = threadIdx.x;
  const int lane = t & 63;
  const int lo = lane & 31;
  const int hi = lane >> 5;
  const int w = t >> 6;
  const int oc0 = (w & 1) * 32;
  const int s = blockIdx.y * 2 + (w >> 1);       // conv tap position 0..63
  const int kh = s >> 3, kw = s & 7;
  const int tg = blockIdx.x * 32 + lo;           // reduced token (A-row m)
  const int b = tg >> 8;
  const int p = tg & 255;
  const int nrow = ((p >> 4) * 8 + kh) * WIMG + (p & 15) * 8 + kw;
  const float* xr = x + ((size_t)b * NTOK + nrow) * CDIM;

  f32x16 c;
  #pragma unroll
  for (int i = 0; i < 16; ++i) c[i] = 0.f;

  #pragma unroll
  for (int f = 0; f < 4; ++f) {
    const int ic = f * 16 + hi * 8;
    float4 a0 = *(const float4*)(xr + ic);
    float4 a1 = *(const float4*)(xr + ic + 4);
    float v[8] = {a0.x, a0.y, a0.z, a0.w, a1.x, a1.y, a1.z, a1.w};
    bf16x8 ah, al;
    split8(v, ah, al);
    // B[k=ic+j][n=oc0+lo]: srw[o][i][s] at o*4096 + i*64 + s
    const float* wb = srw + (size_t)(oc0 + lo) * 4096 + (size_t)ic * 64 + s;
    float bv[8] = {wb[0], wb[64], wb[128], wb[192], wb[256], wb[320], wb[384], wb[448]};
    bf16x8 bh, bl;
    split8(bv, bh, bl);
    c = mfma32x16(ah, bh, c);
    c = mfma32x16(ah, bl, c);
    c = mfma32x16(al, bh, c);
  }
  #pragma unroll
  for (int r = 0; r < 16; ++r) {
    const int tokr = (r & 3) + 8 * (r >> 2) + 4 * hi;   // verified C row map
    pbuf[((size_t)s * RTOKS + blockIdx.x * 32 + tokr) * 64 + oc0 + lo] = c[r];
  }
}

// ---------------- K2: reduce 64 tap-partials + bias + LN + KV proj -> bf16 K (scaled), bf16 V^T
__global__ __launch_bounds__(64) void k2_ln_kv(const float* __restrict__ pbuf,
                                               const float* __restrict__ srb,
                                               const float* __restrict__ lng,
                                               const float* __restrict__ lnb,
                                               const float* __restrict__ kvw,
                                               u16* __restrict__ kbuf,
                                               u16* __restrict__ vbufT) {
  __shared__ float ylds[64];
  const int tg = blockIdx.x;    // 0..511 reduced token
  const int o  = threadIdx.x;   // 0..63 channel
  float y = srb[o];
  #pragma unroll 8
  for (int s = 0; s < NTAP; ++s) y += pbuf[((size_t)s * RTOKS + tg) * 64 + o];
  const float sum   = wave_reduce_sum64(y);
  const float sumsq = wave_reduce_sum64(y * y);
  const float mu  = sum * (1.f / 64.f);
  const float var = sumsq * (1.f / 64.f) - mu * mu;
  const float rstd = rsqrtf(var + 1e-5f);
  const float yn = (y - mu) * rstd * lng[o] + lnb[o];
  ylds[o] = yn;
  __syncthreads();
  float ka = 0.f, va = 0.f;
  #pragma unroll 16
  for (int i = 0; i < 64; ++i) {
    const float yv = ylds[i];
    ka += yv * kvw[i * 128 + o];
    va += yv * kvw[i * 128 + 64 + o];
  }
  const int b = tg >> 8, p = tg & 255;
  const int h = o >> 3, d = o & 7;
  const int bh = b * NHEAD + h;
  kbuf[((size_t)bh * NKV + p) * HDIM + d] = f2bf(ka * KSCALE);
  vbufT[((size_t)bh * HDIM + d) * NKV + p] = f2bf(va);
}

// ---------------- K3: q = x @ q_w (f32 LDS GEMM), stored head-major bf16 [B][H][N][8]
__global__ __launch_bounds__(256) void k3_qproj(const float* __restrict__ x,
                                                const float* __restrict__ qw,
                                                u16* __restrict__ qbuf) {
  __shared__ float xs[64][68];
  __shared__ float wsq[64][68];
  const int t = threadIdx.x;
  const int blk = blockIdx.x;          // 0..511
  const int b = blk >> 8;
  const int tok0 = (blk & 255) * 64;
  const int lr = t >> 2, lc0 = (t & 3) << 4;
  {
    const float* src = x + ((size_t)b * NTOK + tok0 + lr) * CDIM + lc0;
    float4 v0 = *(const float4*)(src);
    float4 v1 = *(const float4*)(src + 4);
    float4 v2 = *(const float4*)(src + 8);
    float4 v3 = *(const float4*)(src + 12);
    *(float4*)&xs[lr][lc0]      = v0;
    *(float4*)&xs[lr][lc0 + 4]  = v1;
    *(float4*)&xs[lr][lc0 + 8]  = v2;
    *(float4*)&xs[lr][lc0 + 12] = v3;
    const float* wsrc = qw + lr * 64 + lc0;
    float4 w0 = *(const float4*)(wsrc);
    float4 w1 = *(const float4*)(wsrc + 4);
    float4 w2 = *(const float4*)(wsrc + 8);
    float4 w3 = *(const float4*)(wsrc + 12);
    *(float4*)&wsq[lr][lc0]      = w0;
    *(float4*)&wsq[lr][lc0 + 4]  = w1;
    *(float4*)&wsq[lr][lc0 + 8]  = w2;
    *(float4*)&wsq[lr][lc0 + 12] = w3;
  }
  __syncthreads();
  const int tok = t >> 2, cb = (t & 3) << 4;
  float acc[16];
  #pragma unroll
  for (int j = 0; j < 16; ++j) acc[j] = 0.f;
  #pragma unroll 16
  for (int c = 0; c < 64; ++c) {
    const float xv = xs[tok][c];
    #pragma unroll
    for (int j = 0; j < 16; ++j) acc[j] += xv * wsq[c][cb + j];
  }
  const int tokg = tok0 + tok;
  #pragma unroll
  for (int g = 0; g < 2; ++g) {
    const int h = (cb >> 3) + g;
    const int bh = b * NHEAD + h;
    u16* dst = qbuf + ((size_t)bh * NTOK + tokg) * HDIM;
    uint4 w;
    w.x = (unsigned)f2bf(acc[g*8+0]) | ((unsigned)f2bf(acc[g*8+1]) << 16);
    w.y = (unsigned)f2bf(acc[g*8+2]) | ((unsigned)f2bf(acc[g*8+3]) << 16);
    w.z = (unsigned)f2bf(acc[g*8+4]) | ((unsigned)f2bf(acc[g*8+5]) << 16);
    w.w = (unsigned)f2bf(acc[g*8+6]) | ((unsigned)f2bf(acc[g*8+7]) << 16);
    *(uint4*)dst = w;
  }
}

// ---------------- K4: round-4 verified MFMA attention (preloaded kf/vf, 4 q-tiles/wave)
__global__ __launch_bounds__(256) void k4_attn_mfma(const u16* __restrict__ qbuf,
                                                    const u16* __restrict__ kbuf,
                                                    const u16* __restrict__ vbufT,
                                                    float* __restrict__ abuf) {
  const int t = threadIdx.x;
  const int lane = t & 63;
  const int w = blockIdx.x * 4 + (t >> 6);   // global wave id, 0..2047
  const int bh = w >> 7;                     // 16 (b,h) pairs, 128 waves each
  const int wi = w & 127;
  const int lo = lane & 31;
  const int hi = lane >> 5;

  // K fragments: A[m=key][k]; hi=0 lanes hold k=0..7 = K row (16B load); hi=1 -> zero pad
  bf16x8 kf[8];
  const u16* kb = kbuf + (size_t)bh * NKV * HDIM;
  #pragma unroll
  for (int c = 0; c < 8; ++c) {
    bf16x8 z = {0, 0, 0, 0, 0, 0, 0, 0};
    if (hi == 0) z = *(const bf16x8*)(kb + (c * 32 + lo) * HDIM);
    kf[c] = z;
  }

  // V^T fragments: A[m=d][k=key]; frag f covers keys f*16..f*16+15; lane supplies
  // k = 8*hi + i -> V^T[lo][f*16 + hi*8 + i] (16B load); rows d>=8 are zero.
  bf16x8 vf[16];
  const u16* vb = vbufT + (size_t)bh * HDIM * NKV;
  #pragma unroll
  for (int f = 0; f < 16; ++f) {
    bf16x8 z = {0, 0, 0, 0, 0, 0, 0, 0};
    if (lo < 8) z = *(const bf16x8*)(vb + lo * NKV + f * 16 + hi * 8);
    vf[f] = z;
  }

  #pragma unroll
  for (int c = 0; c < 4; ++c) {
    const int qt = (wi * 4 + c) * 32;
    // Q^T fragment: B[k][n=query]; hi=0 lanes hold k=0..7 = Q row; hi=1 zero pad
    bf16x8 qf = {0, 0, 0, 0, 0, 0, 0, 0};
    if (hi == 0) qf = *(const bf16x8*)(qbuf + ((size_t)bh * NTOK + qt + lo) * HDIM);

    f32x16 oacc;
    #pragma unroll
    for (int i = 0; i < 16; ++i) oacc[i] = 0.f;
    float den = 0.f;

    #pragma unroll
    for (int kblk = 0; kblk < 8; ++kblk) {
      f32x16 s;
      #pragma unroll
      for (int i = 0; i < 16; ++i) s[i] = 0.f;
      s = mfma32x16(kf[kblk], qf, s);   // S^T tile: rows=keys kblk*32+.., cols=queries

      float p[16];
      #pragma unroll
      for (int r = 0; r < 16; ++r) p[r] = fexp2(s[r]);
      #pragma unroll
      for (int r = 0; r < 16; ++r) den += p[r];

      unsigned pk01[4], pk23[4];
      #pragma unroll
      for (int q = 0; q < 4; ++q) {
        asm("v_cvt_pk_bf16_f32 %0, %1, %2" : "=v"(pk01[q]) : "v"(p[4*q+0]), "v"(p[4*q+1]));
        asm("v_cvt_pk_bf16_f32 %0, %1, %2" : "=v"(pk23[q]) : "v"(p[4*q+2]), "v"(p[4*q+3]));
      }
      #pragma unroll
      for (int jj = 0; jj < 2; ++jj) {
        unsigned a0 = pk01[2*jj], b0 = pk01[2*jj+1];
        unsigned a1 = pk23[2*jj], b1 = pk23[2*jj+1];
        pl32swap(a0, b0);
        pl32swap(a1, b1);
        u32x4 wv; wv[0] = a0; wv[1] = a1; wv[2] = b0; wv[3] = b1;
        bf16x8 pfrag = __builtin_bit_cast(bf16x8, wv);
        oacc = mfma32x16(vf[kblk * 2 + jj], pfrag, oacc);
      }
    }

    den += __shfl_xor(den, 32, 64);
    const float r = 1.0f / den;
    float4 o;
    o.x = oacc[0] * r; o.y = oacc[1] * r; o.z = oacc[2] * r; o.w = oacc[3] * r;
    *(float4*)(abuf + ((size_t)bh * NTOK + qt + lo) * HDIM + hi * 4) = o;
  }
}

// ---------------- K5: output projection + bias (round-4 verified verbatim)
__global__ __launch_bounds__(256) void k5_proj(const float* __restrict__ abuf,
                                               const float* __restrict__ pw,
                                               const float* __restrict__ pb,
                                               float* __restrict__ out) {
  __shared__ float as_[64][68];
  __shared__ float wsp[64][68];
  const int t = threadIdx.x;
  const int blk = blockIdx.x;  // 0..511
  const int b = blk >> 8;
  const int tok0 = (blk & 255) * 64;
  {
    const int h = t >> 5;
    const int rem = (t & 31) << 4;
    const int tokL = rem >> 3;
    const float* src = abuf + (((size_t)b * NHEAD + h) * NTOK + tok0 + tokL) * HDIM;
    float4 v0 = *(const float4*)(src);
    float4 v1 = *(const float4*)(src + 4);
    float4 v2 = *(const float4*)(src + 8);
    float4 v3 = *(const float4*)(src + 12);
    *(float4*)&as_[tokL][h * 8]         = v0;
    *(float4*)&as_[tokL][h * 8 + 4]     = v1;
    *(float4*)&as_[tokL + 1][h * 8]     = v2;
    *(float4*)&as_[tokL + 1][h * 8 + 4] = v3;
    const int wr = t >> 2, wc0 = (t & 3) << 4;
    const float* wsrc = pw + wr * 64 + wc0;
    float4 w0 = *(const float4*)(wsrc);
    float4 w1 = *(const float4*)(wsrc + 4);
    float4 w2 = *(const float4*)(wsrc + 8);
    float4 w3 = *(const float4*)(wsrc + 12);
    *(float4*)&wsp[wr][wc0]      = w0;
    *(float4*)&wsp[wr][wc0 + 4]  = w1;
    *(float4*)&wsp[wr][wc0 + 8]  = w2;
    *(float4*)&wsp[wr][wc0 + 12] = w3;
  }
  __syncthreads();
  const int tok = t >> 2, cb = (t & 3) << 4;
  float acc[16];
  #pragma unroll
  for (int j = 0; j < 16; ++j) acc[j] = 0.f;
  #pragma unroll 16
  for (int c = 0; c < 64; ++c) {
    const float xv = as_[tok][c];
    #pragma unroll
    for (int j = 0; j < 16; ++j) acc[j] += xv * wsp[c][cb + j];
  }
  float* dst = out + ((size_t)b * NTOK + tok0 + tok) * CDIM + cb;
  #pragma unroll
  for (int j = 0; j < 16; ++j) acc[j] += pb[cb + j];
  *(float4*)(dst)      = make_float4(acc[0], acc[1], acc[2], acc[3]);
  *(float4*)(dst + 4)  = make_float4(acc[4], acc[5], acc[6], acc[7]);
  *(float4*)(dst + 8)  = make_float4(acc[8], acc[9], acc[10], acc[11]);
  *(float4*)(dst + 12) = make_float4(acc[12], acc[13], acc[14], acc[15]);
}

extern "C" void kernel_launch(void* const* d_in, const int* in_sizes, int n_in,
                              void* d_out, int out_size, void* d_ws, size_t ws_size,
                              hipStream_t stream) {
  const float* x    = (const float*)d_in[0];
  // d_in[1], d_in[2] are H, W scalars (128, 128) — fixed by the problem
  const float* qw   = (const float*)d_in[3];
  const float* kvw  = (const float*)d_in[4];
  const float* srw  = (const float*)d_in[5];
  const float* srb  = (const float*)d_in[6];
  const float* lng  = (const float*)d_in[7];
  const float* lnb  = (const float*)d_in[8];
  const float* pw   = (const float*)d_in[9];
  const float* pb   = (const float*)d_in[10];
  float* out = (float*)d_out;
  float* ws  = (float*)d_ws;

  float* pbuf  = ws;                        // 64*512*64 = 2097152 floats (8 MB)
  u16*   kbuf  = (u16*)(ws + 2097152);      // 32768 bf16
  u16*   vbufT = (u16*)(ws + 2113536);      // 32768 bf16
  u16*   qbuf  = (u16*)(ws + 2129920);      // 2097152 bf16 (1048576 floats)
  float* abuf  = ws + 3178496;              // 2097152 floats

  kA_conv<<<dim3(16, 32), 256, 0, stream>>>(x, srw, pbuf);
  k2_ln_kv<<<512, 64, 0, stream>>>(pbuf, srb, lng, lnb, kvw, kbuf, vbufT);
  k3_qproj<<<512, 256, 0, stream>>>(x, qw, qbuf);
  k4_attn_mfma<<<512, 256, 0, stream>>>(qbuf, kbuf, vbufT, abuf);
  k5_proj<<<512, 256, 0, stream>>>(abuf, pw, pb, out);
}

// Round 10
// 63.210 us; speedup vs baseline: 1.1548x; 1.0179x over previous
//
#include <hip/hip_runtime.h>
#include <math.h>

#define NB 2
#define NTOK 16384
#define CDIM 64
#define WIMG 128
#define NKV 256
#define NHEAD 8
#define HDIM 8
#define KTOT 4096
#define KSPLIT 16
#define RTOKS 512  // NB*NKV reduced tokens

typedef unsigned short u16;
typedef __attribute__((ext_vector_type(8))) short bf16x8;
typedef __attribute__((ext_vector_type(4))) unsigned int u32x4;
typedef __attribute__((ext_vector_type(2))) unsigned int u32x2;
typedef __attribute__((ext_vector_type(16))) float f32x16;

// softmax scale folded with log2(e), applied to K before bf16 quantization
constexpr float KSCALE = 0.35355339059327373f * 1.4426950408889634f;

__device__ __forceinline__ u16 f2bf(float f) {   // RNE f32->bf16
  unsigned u = __builtin_bit_cast(unsigned, f);
  return (u16)((u + 0x7FFFu + ((u >> 16) & 1u)) >> 16);
}

__device__ __forceinline__ f32x16 mfma32x16(bf16x8 a, bf16x8 b, f32x16 c) {
  return __builtin_amdgcn_mfma_f32_32x32x16_bf16(a, b, c, 0, 0, 0);
}

__device__ __forceinline__ void pl32swap(unsigned &a, unsigned &b) {
  u32x2 r = __builtin_amdgcn_permlane32_swap(a, b, false, false);
  a = r[0]; b = r[1];
}

__device__ __forceinline__ float fexp2(float x) {
  float r;
  asm("v_exp_f32 %0, %1" : "=v"(r) : "v"(x));
  return r;
}

__device__ __forceinline__ float wave_reduce_sum64(float v) {
  #pragma unroll
  for (int off = 32; off > 0; off >>= 1) v += __shfl_xor(v, off, 64);
  return v;
}

// ---------------- K0: transpose conv weight [O][I][8][8] -> W2T[kk][o], kk = pos*64+i
__global__ __launch_bounds__(256) void k0_transpose_w(const float* __restrict__ srw,
                                                      float* __restrict__ w2t) {
  int idx = blockIdx.x * 256 + threadIdx.x;   // 262144 total
  int kk = idx >> 6;
  int o  = idx & 63;
  int pos = kk >> 6;
  int i   = kk & 63;
  w2t[idx] = srw[(o << 12) + (i << 6) + pos];
}

// ---------------- K1: conv as K-split GEMM. grid (16 token tiles, 16 k-chunks)
__global__ __launch_bounds__(256) void k1_conv_partial(const float* __restrict__ x,
                                                       const float* __restrict__ w2t,
                                                       float* __restrict__ pbuf) {
  __shared__ float xs[32][68];
  __shared__ float ws[64][68];
  const int t = threadIdx.x;
  const int tile = blockIdx.x;   // 0..15
  const int kch  = blockIdx.y;   // 0..15
  const int lr = t >> 3, li0 = (t & 7) << 3;     // x: 32 rows x 64
  const int tgL = tile * 32 + lr;
  const int bL  = tgL >> 8;
  const int pL  = tgL & 255;
  const int phL = pL >> 4, pwL = pL & 15;
  const int wr = t >> 2, wo0 = (t & 3) << 4;     // w: 64 rows x 64
  const int tokl = t >> 3;
  const int ob   = (t & 7) << 3;
  float acc[8];
  #pragma unroll
  for (int j = 0; j < 8; ++j) acc[j] = 0.f;

  for (int sc = 0; sc < 4; ++sc) {
    const int k0  = kch * 256 + sc * 64;   // 64-aligned chunk == one conv tap position
    const int pos = k0 >> 6;
    const int kh = pos >> 3, kw = pos & 7;
    const int nrow = (phL * 8 + kh) * WIMG + (pwL * 8 + kw);
    const float* xsrc = x + ((size_t)bL * NTOK + nrow) * CDIM + li0;
    float4 a0 = *(const float4*)(xsrc);
    float4 a1 = *(const float4*)(xsrc + 4);
    const float* wsrc = w2t + (size_t)(k0 + wr) * 64 + wo0;
    float4 b0 = *(const float4*)(wsrc);
    float4 b1 = *(const float4*)(wsrc + 4);
    float4 b2 = *(const float4*)(wsrc + 8);
    float4 b3 = *(const float4*)(wsrc + 12);
    __syncthreads();
    *(float4*)&xs[lr][li0]     = a0;
    *(float4*)&xs[lr][li0 + 4] = a1;
    *(float4*)&ws[wr][wo0]      = b0;
    *(float4*)&ws[wr][wo0 + 4]  = b1;
    *(float4*)&ws[wr][wo0 + 8]  = b2;
    *(float4*)&ws[wr][wo0 + 12] = b3;
    __syncthreads();
    #pragma unroll 16
    for (int kk2 = 0; kk2 < 64; ++kk2) {
      const float xv = xs[tokl][kk2];
      #pragma unroll
      for (int j = 0; j < 8; ++j) acc[j] += xv * ws[kk2][ob + j];
    }
  }
  const int tg = tile * 32 + tokl;
  float* dst = pbuf + ((size_t)kch * RTOKS + tg) * 64 + ob;
  #pragma unroll
  for (int j = 0; j < 8; ++j) dst[j] = acc[j];
}

// ---------------- K2: reduce partials + bias + LN + KV proj -> bf16 K (scaled), bf16 V^T
__global__ __launch_bounds__(64) void k2_ln_kv(const float* __restrict__ pbuf,
                                               const float* __restrict__ srb,
                                               const float* __restrict__ lng,
                                               const float* __restrict__ lnb,
                                               const float* __restrict__ kvw,
                                               u16* __restrict__ kbuf,
                                               u16* __restrict__ vbufT) {
  __shared__ float ylds[64];
  const int tg = blockIdx.x;    // 0..511 reduced token
  const int o  = threadIdx.x;   // 0..63 channel
  float y = srb[o];
  #pragma unroll
  for (int s = 0; s < KSPLIT; ++s) y += pbuf[((size_t)s * RTOKS + tg) * 64 + o];
  const float sum   = wave_reduce_sum64(y);
  const float sumsq = wave_reduce_sum64(y * y);
  const float mu  = sum * (1.f / 64.f);
  const float var = sumsq * (1.f / 64.f) - mu * mu;
  const float rstd = rsqrtf(var + 1e-5f);
  const float yn = (y - mu) * rstd * lng[o] + lnb[o];
  ylds[o] = yn;
  __syncthreads();
  float ka = 0.f, va = 0.f;
  #pragma unroll 16
  for (int i = 0; i < 64; ++i) {
    const float yv = ylds[i];
    ka += yv * kvw[i * 128 + o];
    va += yv * kvw[i * 128 + 64 + o];
  }
  const int b = tg >> 8, p = tg & 255;
  const int h = o >> 3, d = o & 7;
  const int bh = b * NHEAD + h;
  kbuf[((size_t)bh * NKV + p) * HDIM + d] = f2bf(ka * KSCALE);
  vbufT[((size_t)bh * HDIM + d) * NKV + p] = f2bf(va);
}

// ---------------- K3: q = x @ q_w (f32 LDS GEMM), stored head-major bf16 [B][H][N][8]
__global__ __launch_bounds__(256) void k3_qproj(const float* __restrict__ x,
                                                const float* __restrict__ qw,
                                                u16* __restrict__ qbuf) {
  __shared__ float xs[64][68];
  __shared__ float wsq[64][68];
  const int t = threadIdx.x;
  const int blk = blockIdx.x;          // 0..511
  const int b = blk >> 8;
  const int tok0 = (blk & 255) * 64;
  const int lr = t >> 2, lc0 = (t & 3) << 4;
  {
    const float* src = x + ((size_t)b * NTOK + tok0 + lr) * CDIM + lc0;
    float4 v0 = *(const float4*)(src);
    float4 v1 = *(const float4*)(src + 4);
    float4 v2 = *(const float4*)(src + 8);
    float4 v3 = *(const float4*)(src + 12);
    *(float4*)&xs[lr][lc0]      = v0;
    *(float4*)&xs[lr][lc0 + 4]  = v1;
    *(float4*)&xs[lr][lc0 + 8]  = v2;
    *(float4*)&xs[lr][lc0 + 12] = v3;
    const float* wsrc = qw + lr * 64 + lc0;
    float4 w0 = *(const float4*)(wsrc);
    float4 w1 = *(const float4*)(wsrc + 4);
    float4 w2 = *(const float4*)(wsrc + 8);
    float4 w3 = *(const float4*)(wsrc + 12);
    *(float4*)&wsq[lr][lc0]      = w0;
    *(float4*)&wsq[lr][lc0 + 4]  = w1;
    *(float4*)&wsq[lr][lc0 + 8]  = w2;
    *(float4*)&wsq[lr][lc0 + 12] = w3;
  }
  __syncthreads();
  const int tok = t >> 2, cb = (t & 3) << 4;
  float acc[16];
  #pragma unroll
  for (int j = 0; j < 16; ++j) acc[j] = 0.f;
  #pragma unroll 16
  for (int c = 0; c < 64; ++c) {
    const float xv = xs[tok][c];
    #pragma unroll
    for (int j = 0; j < 16; ++j) acc[j] += xv * wsq[c][cb + j];
  }
  const int tokg = tok0 + tok;
  #pragma unroll
  for (int g = 0; g < 2; ++g) {
    const int h = (cb >> 3) + g;
    const int bh = b * NHEAD + h;
    u16* dst = qbuf + ((size_t)bh * NTOK + tokg) * HDIM;
    uint4 w;
    w.x = (unsigned)f2bf(acc[g*8+0]) | ((unsigned)f2bf(acc[g*8+1]) << 16);
    w.y = (unsigned)f2bf(acc[g*8+2]) | ((unsigned)f2bf(acc[g*8+3]) << 16);
    w.z = (unsigned)f2bf(acc[g*8+4]) | ((unsigned)f2bf(acc[g*8+5]) << 16);
    w.w = (unsigned)f2bf(acc[g*8+6]) | ((unsigned)f2bf(acc[g*8+7]) << 16);
    *(uint4*)dst = w;
  }
}

// ---------------- K4 v6: verified MFMA attention core; kf preloaded (32 VGPR),
// vf streamed with one-kblk software prefetch (load for kblk+1 issued before
// kblk's softmax). 2 q-tiles/wave, grid 1024 blocks -> 4 blocks/CU; target
// VGPR <=128 for 4 waves/SIMD. Arithmetic sequence identical to round 4.
__global__ __launch_bounds__(256) void k4_attn_mfma(const u16* __restrict__ qbuf,
                                                    const u16* __restrict__ kbuf,
                                                    const u16* __restrict__ vbufT,
                                                    float* __restrict__ abuf) {
  const int t = threadIdx.x;
  const int lane = t & 63;
  const int w = blockIdx.x * 4 + (t >> 6);   // global wave id, 0..4095
  const int bh = w >> 8;                     // 16 (b,h) pairs, 256 waves each
  const int wi = w & 255;                    // 2 q-tiles per wave
  const int lo = lane & 31;
  const int hi = lane >> 5;

  const u16* kb = kbuf + (size_t)bh * NKV * HDIM;
  const u16* vb = vbufT + (size_t)bh * HDIM * NKV;

  // K fragments: A[m=key][k]; hi=0 lanes hold k=0..7 = K row (16B load); hi=1 -> zero pad
  bf16x8 kf[8];
  #pragma unroll
  for (int c = 0; c < 8; ++c) {
    bf16x8 z = {0, 0, 0, 0, 0, 0, 0, 0};
    if (hi == 0) z = *(const bf16x8*)(kb + (c * 32 + lo) * HDIM);
    kf[c] = z;
  }

  #pragma unroll
  for (int c = 0; c < 2; ++c) {
    const int qt = (wi * 2 + c) * 32;
    // Q^T fragment: B[k][n=query]; hi=0 lanes hold k=0..7 = Q row; hi=1 zero pad
    bf16x8 qf = {0, 0, 0, 0, 0, 0, 0, 0};
    if (hi == 0) qf = *(const bf16x8*)(qbuf + ((size_t)bh * NTOK + qt + lo) * HDIM);

    f32x16 oacc;
    #pragma unroll
    for (int i = 0; i < 16; ++i) oacc[i] = 0.f;
    float den = 0.f;

    // V^T fragment prefetch for kblk=0: A[m=d][k=key]; lane supplies k=8*hi+i;
    // rows d>=8 zero (lanes lo>=8 never load, stay zero).
    bf16x8 vf0n = {0, 0, 0, 0, 0, 0, 0, 0};
    bf16x8 vf1n = {0, 0, 0, 0, 0, 0, 0, 0};
    if (lo < 8) {
      vf0n = *(const bf16x8*)(vb + lo * NKV + 0 + hi * 8);
      vf1n = *(const bf16x8*)(vb + lo * NKV + 16 + hi * 8);
    }

    #pragma unroll
    for (int kblk = 0; kblk < 8; ++kblk) {
      const bf16x8 vf0 = vf0n;
      const bf16x8 vf1 = vf1n;
      if (kblk < 7 && lo < 8) {   // prefetch next kblk's V fragments
        vf0n = *(const bf16x8*)(vb + lo * NKV + (kblk + 1) * 32 + hi * 8);
        vf1n = *(const bf16x8*)(vb + lo * NKV + (kblk + 1) * 32 + 16 + hi * 8);
      }

      f32x16 s;
      #pragma unroll
      for (int i = 0; i < 16; ++i) s[i] = 0.f;
      s = mfma32x16(kf[kblk], qf, s);   // S^T tile: rows=keys kblk*32+.., cols=queries

      float p[16];
      #pragma unroll
      for (int r = 0; r < 16; ++r) p[r] = fexp2(s[r]);
      #pragma unroll
      for (int r = 0; r < 16; ++r) den += p[r];

      unsigned pk01[4], pk23[4];
      #pragma unroll
      for (int q = 0; q < 4; ++q) {
        asm("v_cvt_pk_bf16_f32 %0, %1, %2" : "=v"(pk01[q]) : "v"(p[4*q+0]), "v"(p[4*q+1]));
        asm("v_cvt_pk_bf16_f32 %0, %1, %2" : "=v"(pk23[q]) : "v"(p[4*q+2]), "v"(p[4*q+3]));
      }
      {
        unsigned a0 = pk01[0], b0 = pk01[1];
        unsigned a1 = pk23[0], b1 = pk23[1];
        pl32swap(a0, b0);
        pl32swap(a1, b1);
        u32x4 wv; wv[0] = a0; wv[1] = a1; wv[2] = b0; wv[3] = b1;
        bf16x8 pfrag = __builtin_bit_cast(bf16x8, wv);
        oacc = mfma32x16(vf0, pfrag, oacc);
      }
      {
        unsigned a0 = pk01[2], b0 = pk01[3];
        unsigned a1 = pk23[2], b1 = pk23[3];
        pl32swap(a0, b0);
        pl32swap(a1, b1);
        u32x4 wv; wv[0] = a0; wv[1] = a1; wv[2] = b0; wv[3] = b1;
        bf16x8 pfrag = __builtin_bit_cast(bf16x8, wv);
        oacc = mfma32x16(vf1, pfrag, oacc);
      }
    }

    // epilogue: O^T col=query=lo; regs0-3 = d(0..3|4..7 by hi); den: this lane's
    // 16 S^T rows + partner's 16.
    den += __shfl_xor(den, 32, 64);
    const float r = 1.0f / den;
    float4 o;
    o.x = oacc[0] * r; o.y = oacc[1] * r; o.z = oacc[2] * r; o.w = oacc[3] * r;
    *(float4*)(abuf + ((size_t)bh * NTOK + qt + lo) * HDIM + hi * 4) = o;
  }
}

// ---------------- K5: output projection + bias (round-4 verified verbatim)
__global__ __launch_bounds__(256) void k5_proj(const float* __restrict__ abuf,
                                               const float* __restrict__ pw,
                                               const float* __restrict__ pb,
                                               float* __restrict__ out) {
  __shared__ float as_[64][68];
  __shared__ float wsp[64][68];
  const int t = threadIdx.x;
  const int blk = blockIdx.x;  // 0..511
  const int b = blk >> 8;
  const int tok0 = (blk & 255) * 64;
  {
    const int h = t >> 5;
    const int rem = (t & 31) << 4;
    const int tokL = rem >> 3;
    const float* src = abuf + (((size_t)b * NHEAD + h) * NTOK + tok0 + tokL) * HDIM;
    float4 v0 = *(const float4*)(src);
    float4 v1 = *(const float4*)(src + 4);
    float4 v2 = *(const float4*)(src + 8);
    float4 v3 = *(const float4*)(src + 12);
    *(float4*)&as_[tokL][h * 8]         = v0;
    *(float4*)&as_[tokL][h * 8 + 4]     = v1;
    *(float4*)&as_[tokL + 1][h * 8]     = v2;
    *(float4*)&as_[tokL + 1][h * 8 + 4] = v3;
    const int wr = t >> 2, wc0 = (t & 3) << 4;
    const float* wsrc = pw + wr * 64 + wc0;
    float4 w0 = *(const float4*)(wsrc);
    float4 w1 = *(const float4*)(wsrc + 4);
    float4 w2 = *(const float4*)(wsrc + 8);
    float4 w3 = *(const float4*)(wsrc + 12);
    *(float4*)&wsp[wr][wc0]      = w0;
    *(float4*)&wsp[wr][wc0 + 4]  = w1;
    *(float4*)&wsp[wr][wc0 + 8]  = w2;
    *(float4*)&wsp[wr][wc0 + 12] = w3;
  }
  __syncthreads();
  const int tok = t >> 2, cb = (t & 3) << 4;
  float acc[16];
  #pragma unroll
  for (int j = 0; j < 16; ++j) acc[j] = 0.f;
  #pragma unroll 16
  for (int c = 0; c < 64; ++c) {
    const float xv = as_[tok][c];
    #pragma unroll
    for (int j = 0; j < 16; ++j) acc[j] += xv * wsp[c][cb + j];
  }
  float* dst = out + ((size_t)b * NTOK + tok0 + tok) * CDIM + cb;
  #pragma unroll
  for (int j = 0; j < 16; ++j) acc[j] += pb[cb + j];
  *(float4*)(dst)      = make_float4(acc[0], acc[1], acc[2], acc[3]);
  *(float4*)(dst + 4)  = make_float4(acc[4], acc[5], acc[6], acc[7]);
  *(float4*)(dst + 8)  = make_float4(acc[8], acc[9], acc[10], acc[11]);
  *(float4*)(dst + 12) = make_float4(acc[12], acc[13], acc[14], acc[15]);
}

extern "C" void kernel_launch(void* const* d_in, const int* in_sizes, int n_in,
                              void* d_out, int out_size, void* d_ws, size_t ws_size,
                              hipStream_t stream) {
  const float* x    = (const float*)d_in[0];
  // d_in[1], d_in[2] are H, W scalars (128, 128) — fixed by the problem
  const float* qw   = (const float*)d_in[3];
  const float* kvw  = (const float*)d_in[4];
  const float* srw  = (const float*)d_in[5];
  const float* srb  = (const float*)d_in[6];
  const float* lng  = (const float*)d_in[7];
  const float* lnb  = (const float*)d_in[8];
  const float* pw   = (const float*)d_in[9];
  const float* pb   = (const float*)d_in[10];
  float* out = (float*)d_out;
  float* ws  = (float*)d_ws;

  float* w2t   = ws;                        // 262144 floats
  float* pbuf  = ws + 262144;               // 524288 floats
  u16*   kbuf  = (u16*)(ws + 786432);       // 32768 bf16  (16384 floats)
  u16*   vbufT = (u16*)(ws + 802816);       // 32768 bf16  (16384 floats)
  u16*   qbuf  = (u16*)(ws + 819200);       // 2097152 bf16 (1048576 floats)
  float* abuf  = ws + 1867776;              // 2097152 floats

  k0_transpose_w<<<1024, 256, 0, stream>>>(srw, w2t);
  k1_conv_partial<<<dim3(16, 16), 256, 0, stream>>>(x, w2t, pbuf);
  k2_ln_kv<<<512, 64, 0, stream>>>(pbuf, srb, lng, lnb, kvw, kbuf, vbufT);
  k3_qproj<<<512, 256, 0, stream>>>(x, qw, qbuf);
  k4_attn_mfma<<<1024, 256, 0, stream>>>(qbuf, kbuf, vbufT, abuf);
  k5_proj<<<512, 256, 0, stream>>>(abuf, pw, pb, out);
}

// Round 11
// 46.988 us; speedup vs baseline: 1.5535x; 1.3452x over previous
//
#include <hip/hip_runtime.h>
#include <math.h>

#define NB 2
#define NTOK 16384
#define CDIM 64
#define WIMG 128
#define NKV 256
#define NHEAD 8
#define HDIM 8
#define RTOKS 512   // NB*NKV reduced tokens
#define NSLICE 32   // conv partial slices (16 kchunks x 2 tap-pairs)

typedef unsigned short u16;
typedef __attribute__((ext_vector_type(8))) short bf16x8;
typedef __attribute__((ext_vector_type(4))) unsigned int u32x4;
typedef __attribute__((ext_vector_type(2))) unsigned int u32x2;
typedef __attribute__((ext_vector_type(16))) float f32x16;

// softmax scale folded with log2(e), applied to K before bf16 quantization
constexpr float KSCALE = 0.35355339059327373f * 1.4426950408889634f;

__device__ __forceinline__ u16 f2bf(float f) {   // RNE f32->bf16
  unsigned u = __builtin_bit_cast(unsigned, f);
  return (u16)((u + 0x7FFFu + ((u >> 16) & 1u)) >> 16);
}
__device__ __forceinline__ float bf2f(u16 h) {
  return __builtin_bit_cast(float, (unsigned)h << 16);
}

__device__ __forceinline__ f32x16 mfma32x16(bf16x8 a, bf16x8 b, f32x16 c) {
  return __builtin_amdgcn_mfma_f32_32x32x16_bf16(a, b, c, 0, 0, 0);
}

__device__ __forceinline__ void pl32swap(unsigned &a, unsigned &b) {
  u32x2 r = __builtin_amdgcn_permlane32_swap(a, b, false, false);
  a = r[0]; b = r[1];
}

__device__ __forceinline__ float fexp2(float x) {
  float r;
  asm("v_exp_f32 %0, %1" : "=v"(r) : "v"(x));
  return r;
}

// split 8 f32 into hi/lo bf16 fragments: v ~= hi + lo
__device__ __forceinline__ void split8(const float* v, bf16x8& hout, bf16x8& lout) {
  unsigned hw[4], lw[4];
  float hf[8], lof[8];
  #pragma unroll
  for (int q = 0; q < 4; ++q)
    asm("v_cvt_pk_bf16_f32 %0, %1, %2" : "=v"(hw[q]) : "v"(v[2*q]), "v"(v[2*q+1]));
  #pragma unroll
  for (int q = 0; q < 4; ++q) {
    hf[2*q]   = __builtin_bit_cast(float, hw[q] << 16);
    hf[2*q+1] = __builtin_bit_cast(float, hw[q] & 0xFFFF0000u);
  }
  #pragma unroll
  for (int j = 0; j < 8; ++j) lof[j] = v[j] - hf[j];
  #pragma unroll
  for (int q = 0; q < 4; ++q)
    asm("v_cvt_pk_bf16_f32 %0, %1, %2" : "=v"(lw[q]) : "v"(lof[2*q]), "v"(lof[2*q+1]));
  u32x4 H; H[0] = hw[0]; H[1] = hw[1]; H[2] = hw[2]; H[3] = hw[3];
  u32x4 L; L[0] = lw[0]; L[1] = lw[1]; L[2] = lw[2]; L[3] = lw[3];
  hout = __builtin_bit_cast(bf16x8, H);
  lout = __builtin_bit_cast(bf16x8, L);
}

__device__ __forceinline__ float wave_reduce_sum64(float v) {
  #pragma unroll
  for (int off = 32; off > 0; off >>= 1) v += __shfl_xor(v, off, 64);
  return v;
}

// ---------------- k0p: pack all weights into MFMA-B-operand bf16 hi/lo layouts.
// conv: wpk[(((s*4+icg)*2+hi)*64+oc)*8+j]  = srw[oc][icg*16+hi*8+j][s]
// qw:   qpk[((icg*2+hi)*64+o)*8+j]         = qw[icg*16+hi*8+j][o]
// pw:   ppk[((g*2+hi)*64+o)*8+j]           = pw[g*16+hi*8+j][o]
__global__ __launch_bounds__(256) void k0_pack(const float* __restrict__ srw,
                                               const float* __restrict__ qw,
                                               const float* __restrict__ pw,
                                               u16* __restrict__ wpk_hi, u16* __restrict__ wpk_lo,
                                               u16* __restrict__ qpk_hi, u16* __restrict__ qpk_lo,
                                               u16* __restrict__ ppk_hi, u16* __restrict__ ppk_lo) {
  int idx = blockIdx.x * 256 + threadIdx.x;   // 270336 total = 1056*256
  if (idx < 262144) {
    const int j   = idx & 7;
    const int oc  = (idx >> 3) & 63;
    const int hi  = (idx >> 9) & 1;
    const int icg = (idx >> 10) & 3;
    const int s   = idx >> 12;
    const float v = srw[oc * 4096 + (icg * 16 + hi * 8 + j) * 64 + s];
    const u16 h = f2bf(v);
    wpk_hi[idx] = h;
    wpk_lo[idx] = f2bf(v - bf2f(h));
  } else if (idx < 262144 + 4096) {
    const int q = idx - 262144;
    const int j   = q & 7;
    const int o   = (q >> 3) & 63;
    const int hi  = (q >> 9) & 1;
    const int icg = q >> 10;
    const float v = qw[(icg * 16 + hi * 8 + j) * 64 + o];
    const u16 h = f2bf(v);
    qpk_hi[q] = h;
    qpk_lo[q] = f2bf(v - bf2f(h));
  } else if (idx < 262144 + 8192) {
    const int q = idx - 262144 - 4096;
    const int j  = q & 7;
    const int o  = (q >> 3) & 63;
    const int hi = (q >> 9) & 1;
    const int g  = q >> 10;
    const float v = pw[(g * 16 + hi * 8 + j) * 64 + o];
    const u16 h = f2bf(v);
    ppk_hi[q] = h;
    ppk_lo[q] = f2bf(v - bf2f(h));
  }
}

// ---------------- kA2: conv partials via split-bf16 MFMA, coalesced packed weights.
// grid(16 token-tiles, 16 kchunks), 256 thr = 4 waves: wave -> (oc-half, tap-pair).
// Each wave: 2 taps x 4 icg x 3 mfma = 24 mfma -> pbuf slice kc*2+th.
__global__ __launch_bounds__(256) void kA2_conv(const float* __restrict__ x,
                                                const u16* __restrict__ wpk_hi,
                                                const u16* __restrict__ wpk_lo,
                                                float* __restrict__ pbuf) {
  const int t = threadIdx.x;
  const int lane = t & 63;
  const int lo = lane & 31;
  const int hi = lane >> 5;
  const int w = t >> 6;
  const int oc0 = (w & 1) * 32;
  const int th = w >> 1;                  // tap-pair within chunk
  const int tile = blockIdx.x;
  const int kc = blockIdx.y;
  const int tg = tile * 32 + lo;          // reduced token (A-row m)
  const int b = tg >> 8;
  const int p = tg & 255;

  f32x16 c;
  #pragma unroll
  for (int i = 0; i < 16; ++i) c[i] = 0.f;

  #pragma unroll
  for (int sp = 0; sp < 2; ++sp) {
    const int s = kc * 4 + th * 2 + sp;   // conv tap 0..63
    const int kh = s >> 3, kw = s & 7;
    const int nrow = ((p >> 4) * 8 + kh) * WIMG + (p & 15) * 8 + kw;
    const float* xr = x + ((size_t)b * NTOK + nrow) * CDIM;
    #pragma unroll
    for (int icg = 0; icg < 4; ++icg) {
      const int ic0 = icg * 16 + hi * 8;
      float4 a0 = *(const float4*)(xr + ic0);
      float4 a1 = *(const float4*)(xr + ic0 + 4);
      float v[8] = {a0.x, a0.y, a0.z, a0.w, a1.x, a1.y, a1.z, a1.w};
      bf16x8 ah, al;
      split8(v, ah, al);
      const size_t widx = ((((size_t)s * 4 + icg) * 2 + hi) * 64 + (oc0 + lo)) * 8;
      bf16x8 bh = *(const bf16x8*)(wpk_hi + widx);
      bf16x8 bl = *(const bf16x8*)(wpk_lo + widx);
      c = mfma32x16(ah, bh, c);
      c = mfma32x16(ah, bl, c);
      c = mfma32x16(al, bh, c);
    }
  }
  const int slice = kc * 2 + th;
  #pragma unroll
  for (int r = 0; r < 16; ++r) {
    const int tokr = (r & 3) + 8 * (r >> 2) + 4 * hi;   // verified C row map
    pbuf[((size_t)slice * RTOKS + tile * 32 + tokr) * 64 + oc0 + lo] = c[r];
  }
}

// ---------------- K2: reduce 32 slices + bias + LN + KV proj -> bf16 K (scaled), bf16 V^T
__global__ __launch_bounds__(64) void k2_ln_kv(const float* __restrict__ pbuf,
                                               const float* __restrict__ srb,
                                               const float* __restrict__ lng,
                                               const float* __restrict__ lnb,
                                               const float* __restrict__ kvw,
                                               u16* __restrict__ kbuf,
                                               u16* __restrict__ vbufT) {
  __shared__ float ylds[64];
  const int tg = blockIdx.x;    // 0..511 reduced token
  const int o  = threadIdx.x;   // 0..63 channel
  float y = srb[o];
  #pragma unroll 8
  for (int s = 0; s < NSLICE; ++s) y += pbuf[((size_t)s * RTOKS + tg) * 64 + o];
  const float sum   = wave_reduce_sum64(y);
  const float sumsq = wave_reduce_sum64(y * y);
  const float mu  = sum * (1.f / 64.f);
  const float var = sumsq * (1.f / 64.f) - mu * mu;
  const float rstd = rsqrtf(var + 1e-5f);
  const float yn = (y - mu) * rstd * lng[o] + lnb[o];
  ylds[o] = yn;
  __syncthreads();
  float ka = 0.f, va = 0.f;
  #pragma unroll 16
  for (int i = 0; i < 64; ++i) {
    const float yv = ylds[i];
    ka += yv * kvw[i * 128 + o];
    va += yv * kvw[i * 128 + 64 + o];
  }
  const int b = tg >> 8, pp = tg & 255;
  const int h = o >> 3, d = o & 7;
  const int bh = b * NHEAD + h;
  kbuf[((size_t)bh * NKV + pp) * HDIM + d] = f2bf(ka * KSCALE);
  vbufT[((size_t)bh * HDIM + d) * NKV + pp] = f2bf(va);
}

// ---------------- kQ: q = x @ qw via split-bf16 MFMA -> bf16 qbuf [B][H][N][8].
// grid 512, 256 thr = 4 waves: wave -> (oc-half, token-tile-half).
__global__ __launch_bounds__(256) void kQ_qproj(const float* __restrict__ x,
                                                const u16* __restrict__ qpk_hi,
                                                const u16* __restrict__ qpk_lo,
                                                u16* __restrict__ qbuf) {
  const int t = threadIdx.x;
  const int lane = t & 63;
  const int lo = lane & 31;
  const int hi = lane >> 5;
  const int w = t >> 6;
  const int oc0 = (w & 1) * 32;
  const int blk = blockIdx.x;
  const int b = blk >> 8;
  const int tok0 = ((blk & 255) * 2 + (w >> 1)) * 32;

  f32x16 c;
  #pragma unroll
  for (int i = 0; i < 16; ++i) c[i] = 0.f;

  const float* xr = x + ((size_t)b * NTOK + tok0 + lo) * CDIM;
  #pragma unroll
  for (int icg = 0; icg < 4; ++icg) {
    const int ic0 = icg * 16 + hi * 8;
    float4 a0 = *(const float4*)(xr + ic0);
    float4 a1 = *(const float4*)(xr + ic0 + 4);
    float v[8] = {a0.x, a0.y, a0.z, a0.w, a1.x, a1.y, a1.z, a1.w};
    bf16x8 ah, al;
    split8(v, ah, al);
    const size_t qidx = (((size_t)icg * 2 + hi) * 64 + (oc0 + lo)) * 8;
    bf16x8 bh = *(const bf16x8*)(qpk_hi + qidx);
    bf16x8 bl = *(const bf16x8*)(qpk_lo + qidx);
    c = mfma32x16(ah, bh, c);
    c = mfma32x16(ah, bl, c);
    c = mfma32x16(al, bh, c);
  }
  // C[m=tok][n=oc]: lane col oc = oc0+lo; row map verified.
  const int oc = oc0 + lo;
  const int h = oc >> 3, d = oc & 7;
  u16* qb = qbuf + (((size_t)b * NHEAD + h) * NTOK) * HDIM + d;
  #pragma unroll
  for (int r = 0; r < 16; ++r) {
    const int tok = tok0 + (r & 3) + 8 * (r >> 2) + 4 * hi;
    qb[(size_t)tok * HDIM] = f2bf(c[r]);
  }
}

// ---------------- K4: round-4 verified MFMA attention (frozen structure)
__global__ __launch_bounds__(256) void k4_attn_mfma(const u16* __restrict__ qbuf,
                                                    const u16* __restrict__ kbuf,
                                                    const u16* __restrict__ vbufT,
                                                    float* __restrict__ abuf) {
  const int t = threadIdx.x;
  const int lane = t & 63;
  const int w = blockIdx.x * 4 + (t >> 6);   // global wave id, 0..2047
  const int bh = w >> 7;                     // 16 (b,h) pairs, 128 waves each
  const int wi = w & 127;
  const int lo = lane & 31;
  const int hi = lane >> 5;

  bf16x8 kf[8];
  const u16* kb = kbuf + (size_t)bh * NKV * HDIM;
  #pragma unroll
  for (int c = 0; c < 8; ++c) {
    bf16x8 z = {0, 0, 0, 0, 0, 0, 0, 0};
    if (hi == 0) z = *(const bf16x8*)(kb + (c * 32 + lo) * HDIM);
    kf[c] = z;
  }

  bf16x8 vf[16];
  const u16* vb = vbufT + (size_t)bh * HDIM * NKV;
  #pragma unroll
  for (int f = 0; f < 16; ++f) {
    bf16x8 z = {0, 0, 0, 0, 0, 0, 0, 0};
    if (lo < 8) z = *(const bf16x8*)(vb + lo * NKV + f * 16 + hi * 8);
    vf[f] = z;
  }

  #pragma unroll
  for (int c = 0; c < 4; ++c) {
    const int qt = (wi * 4 + c) * 32;
    bf16x8 qf = {0, 0, 0, 0, 0, 0, 0, 0};
    if (hi == 0) qf = *(const bf16x8*)(qbuf + ((size_t)bh * NTOK + qt + lo) * HDIM);

    f32x16 oacc;
    #pragma unroll
    for (int i = 0; i < 16; ++i) oacc[i] = 0.f;
    float den = 0.f;

    #pragma unroll
    for (int kblk = 0; kblk < 8; ++kblk) {
      f32x16 s;
      #pragma unroll
      for (int i = 0; i < 16; ++i) s[i] = 0.f;
      s = mfma32x16(kf[kblk], qf, s);   // S^T tile

      float p[16];
      #pragma unroll
      for (int r = 0; r < 16; ++r) p[r] = fexp2(s[r]);
      #pragma unroll
      for (int r = 0; r < 16; ++r) den += p[r];

      unsigned pk01[4], pk23[4];
      #pragma unroll
      for (int q = 0; q < 4; ++q) {
        asm("v_cvt_pk_bf16_f32 %0, %1, %2" : "=v"(pk01[q]) : "v"(p[4*q+0]), "v"(p[4*q+1]));
        asm("v_cvt_pk_bf16_f32 %0, %1, %2" : "=v"(pk23[q]) : "v"(p[4*q+2]), "v"(p[4*q+3]));
      }
      #pragma unroll
      for (int jj = 0; jj < 2; ++jj) {
        unsigned a0 = pk01[2*jj], b0 = pk01[2*jj+1];
        unsigned a1 = pk23[2*jj], b1 = pk23[2*jj+1];
        pl32swap(a0, b0);
        pl32swap(a1, b1);
        u32x4 wv; wv[0] = a0; wv[1] = a1; wv[2] = b0; wv[3] = b1;
        bf16x8 pfrag = __builtin_bit_cast(bf16x8, wv);
        oacc = mfma32x16(vf[kblk * 2 + jj], pfrag, oacc);
      }
    }

    den += __shfl_xor(den, 32, 64);
    const float r = 1.0f / den;
    float4 o;
    o.x = oacc[0] * r; o.y = oacc[1] * r; o.z = oacc[2] * r; o.w = oacc[3] * r;
    *(float4*)(abuf + ((size_t)bh * NTOK + qt + lo) * HDIM + hi * 4) = o;
  }
}

// ---------------- kP: out = O @ pw + pb via split-bf16 MFMA (f32-quality O split on the fly).
// grid 512, 256 thr = 4 waves: wave -> (oc-half, token-tile-half). Coalesced C store.
__global__ __launch_bounds__(256) void kP_proj(const float* __restrict__ abuf,
                                               const u16* __restrict__ ppk_hi,
                                               const u16* __restrict__ ppk_lo,
                                               const float* __restrict__ pb,
                                               float* __restrict__ out) {
  const int t = threadIdx.x;
  const int lane = t & 63;
  const int lo = lane & 31;
  const int hi = lane >> 5;
  const int w = t >> 6;
  const int oc0 = (w & 1) * 32;
  const int blk = blockIdx.x;
  const int b = blk >> 8;
  const int tok0 = ((blk & 255) * 2 + (w >> 1)) * 32;

  f32x16 c;
  #pragma unroll
  for (int i = 0; i < 16; ++i) c[i] = 0.f;

  #pragma unroll
  for (int f = 0; f < 4; ++f) {
    const int h = 2 * f + hi;                 // attention-output channel group = head
    const float* src = abuf + (((size_t)b * NHEAD + h) * NTOK + tok0 + lo) * HDIM;
    float4 a0 = *(const float4*)(src);
    float4 a1 = *(const float4*)(src + 4);
    float v[8] = {a0.x, a0.y, a0.z, a0.w, a1.x, a1.y, a1.z, a1.w};
    bf16x8 ah, al;
    split8(v, ah, al);
    const size_t pidx = (((size_t)f * 2 + hi) * 64 + (oc0 + lo)) * 8;
    bf16x8 bh = *(const bf16x8*)(ppk_hi + pidx);
    bf16x8 bl = *(const bf16x8*)(ppk_lo + pidx);
    c = mfma32x16(ah, bh, c);
    c = mfma32x16(ah, bl, c);
    c = mfma32x16(al, bh, c);
  }
  const float pbv = pb[oc0 + lo];
  #pragma unroll
  for (int r = 0; r < 16; ++r) {
    const int tok = tok0 + (r & 3) + 8 * (r >> 2) + 4 * hi;
    out[((size_t)b * NTOK + tok) * CDIM + oc0 + lo] = c[r] + pbv;
  }
}

extern "C" void kernel_launch(void* const* d_in, const int* in_sizes, int n_in,
                              void* d_out, int out_size, void* d_ws, size_t ws_size,
                              hipStream_t stream) {
  const float* x    = (const float*)d_in[0];
  // d_in[1], d_in[2] are H, W scalars (128, 128) — fixed by the problem
  const float* qw   = (const float*)d_in[3];
  const float* kvw  = (const float*)d_in[4];
  const float* srw  = (const float*)d_in[5];
  const float* srb  = (const float*)d_in[6];
  const float* lng  = (const float*)d_in[7];
  const float* lnb  = (const float*)d_in[8];
  const float* pw   = (const float*)d_in[9];
  const float* pb   = (const float*)d_in[10];
  float* out = (float*)d_out;
  char* base = (char*)d_ws;

  u16*   wpk_hi = (u16*)(base);               // 524288 B
  u16*   wpk_lo = (u16*)(base + 524288);      // 524288 B
  u16*   qpk_hi = (u16*)(base + 1048576);     // 8192 B
  u16*   qpk_lo = (u16*)(base + 1056768);     // 8192 B
  u16*   ppk_hi = (u16*)(base + 1064960);     // 8192 B
  u16*   ppk_lo = (u16*)(base + 1073152);     // 8192 B
  float* pbuf   = (float*)(base + 1081344);   // 32*512*64 f32 = 4194304 B
  u16*   kbuf   = (u16*)(base + 5275648);     // 65536 B
  u16*   vbufT  = (u16*)(base + 5341184);     // 65536 B
  u16*   qbuf   = (u16*)(base + 5406720);     // 4194304 B
  float* abuf   = (float*)(base + 9601024);   // 8388608 B

  k0_pack<<<1056, 256, 0, stream>>>(srw, qw, pw, wpk_hi, wpk_lo,
                                    qpk_hi, qpk_lo, ppk_hi, ppk_lo);
  kA2_conv<<<dim3(16, 16), 256, 0, stream>>>(x, wpk_hi, wpk_lo, pbuf);
  k2_ln_kv<<<512, 64, 0, stream>>>(pbuf, srb, lng, lnb, kvw, kbuf, vbufT);
  kQ_qproj<<<512, 256, 0, stream>>>(x, qpk_hi, qpk_lo, qbuf);
  k4_attn_mfma<<<512, 256, 0, stream>>>(qbuf, kbuf, vbufT, abuf);
  kP_proj<<<512, 256, 0, stream>>>(abuf, ppk_hi, ppk_lo, pb, out);
}

// Round 12
// 46.102 us; speedup vs baseline: 1.5834x; 1.0192x over previous
//
#include <hip/hip_runtime.h>
#include <math.h>

#define NB 2
#define NTOK 16384
#define CDIM 64
#define WIMG 128
#define NKV 256
#define NHEAD 8
#define HDIM 8
#define RTOKS 512   // NB*NKV reduced tokens
#define NSLICE 32   // conv partial slices (16 kchunks x 2 tap-pairs)

typedef unsigned short u16;
typedef __attribute__((ext_vector_type(8))) short bf16x8;
typedef __attribute__((ext_vector_type(4))) unsigned int u32x4;
typedef __attribute__((ext_vector_type(2))) unsigned int u32x2;
typedef __attribute__((ext_vector_type(16))) float f32x16;

// softmax scale folded with log2(e), applied to K before bf16 quantization
constexpr float KSCALE = 0.35355339059327373f * 1.4426950408889634f;

__device__ __forceinline__ u16 f2bf(float f) {   // RNE f32->bf16
  unsigned u = __builtin_bit_cast(unsigned, f);
  return (u16)((u + 0x7FFFu + ((u >> 16) & 1u)) >> 16);
}
__device__ __forceinline__ float bf2f(u16 h) {
  return __builtin_bit_cast(float, (unsigned)h << 16);
}

__device__ __forceinline__ f32x16 mfma32x16(bf16x8 a, bf16x8 b, f32x16 c) {
  return __builtin_amdgcn_mfma_f32_32x32x16_bf16(a, b, c, 0, 0, 0);
}

__device__ __forceinline__ void pl32swap(unsigned &a, unsigned &b) {
  u32x2 r = __builtin_amdgcn_permlane32_swap(a, b, false, false);
  a = r[0]; b = r[1];
}

__device__ __forceinline__ float fexp2(float x) {
  float r;
  asm("v_exp_f32 %0, %1" : "=v"(r) : "v"(x));
  return r;
}

// split 8 f32 into hi/lo bf16 fragments: v ~= hi + lo
__device__ __forceinline__ void split8(const float* v, bf16x8& hout, bf16x8& lout) {
  unsigned hw[4], lw[4];
  float hf[8], lof[8];
  #pragma unroll
  for (int q = 0; q < 4; ++q)
    asm("v_cvt_pk_bf16_f32 %0, %1, %2" : "=v"(hw[q]) : "v"(v[2*q]), "v"(v[2*q+1]));
  #pragma unroll
  for (int q = 0; q < 4; ++q) {
    hf[2*q]   = __builtin_bit_cast(float, hw[q] << 16);
    hf[2*q+1] = __builtin_bit_cast(float, hw[q] & 0xFFFF0000u);
  }
  #pragma unroll
  for (int j = 0; j < 8; ++j) lof[j] = v[j] - hf[j];
  #pragma unroll
  for (int q = 0; q < 4; ++q)
    asm("v_cvt_pk_bf16_f32 %0, %1, %2" : "=v"(lw[q]) : "v"(lof[2*q]), "v"(lof[2*q+1]));
  u32x4 H; H[0] = hw[0]; H[1] = hw[1]; H[2] = hw[2]; H[3] = hw[3];
  u32x4 L; L[0] = lw[0]; L[1] = lw[1]; L[2] = lw[2]; L[3] = lw[3];
  hout = __builtin_bit_cast(bf16x8, H);
  lout = __builtin_bit_cast(bf16x8, L);
}

__device__ __forceinline__ float wave_reduce_sum64(float v) {
  #pragma unroll
  for (int off = 32; off > 0; off >>= 1) v += __shfl_xor(v, off, 64);
  return v;
}

// ---------------- k0p: pack all weights into MFMA-B-operand bf16 hi/lo layouts.
__global__ __launch_bounds__(256) void k0_pack(const float* __restrict__ srw,
                                               const float* __restrict__ qw,
                                               const float* __restrict__ pw,
                                               u16* __restrict__ wpk_hi, u16* __restrict__ wpk_lo,
                                               u16* __restrict__ qpk_hi, u16* __restrict__ qpk_lo,
                                               u16* __restrict__ ppk_hi, u16* __restrict__ ppk_lo) {
  int idx = blockIdx.x * 256 + threadIdx.x;   // 270336 total = 1056*256
  if (idx < 262144) {
    const int j   = idx & 7;
    const int oc  = (idx >> 3) & 63;
    const int hi  = (idx >> 9) & 1;
    const int icg = (idx >> 10) & 3;
    const int s   = idx >> 12;
    const float v = srw[oc * 4096 + (icg * 16 + hi * 8 + j) * 64 + s];
    const u16 h = f2bf(v);
    wpk_hi[idx] = h;
    wpk_lo[idx] = f2bf(v - bf2f(h));
  } else if (idx < 262144 + 4096) {
    const int q = idx - 262144;
    const int j   = q & 7;
    const int o   = (q >> 3) & 63;
    const int hi  = (q >> 9) & 1;
    const int icg = q >> 10;
    const float v = qw[(icg * 16 + hi * 8 + j) * 64 + o];
    const u16 h = f2bf(v);
    qpk_hi[q] = h;
    qpk_lo[q] = f2bf(v - bf2f(h));
  } else if (idx < 262144 + 8192) {
    const int q = idx - 262144 - 4096;
    const int j  = q & 7;
    const int o  = (q >> 3) & 63;
    const int hi = (q >> 9) & 1;
    const int g  = q >> 10;
    const float v = pw[(g * 16 + hi * 8 + j) * 64 + o];
    const u16 h = f2bf(v);
    ppk_hi[q] = h;
    ppk_lo[q] = f2bf(v - bf2f(h));
  }
}

// ---------------- kA2: conv partials via split-bf16 MFMA, coalesced packed weights.
__global__ __launch_bounds__(256) void kA2_conv(const float* __restrict__ x,
                                                const u16* __restrict__ wpk_hi,
                                                const u16* __restrict__ wpk_lo,
                                                float* __restrict__ pbuf) {
  const int t = threadIdx.x;
  const int lane = t & 63;
  const int lo = lane & 31;
  const int hi = lane >> 5;
  const int w = t >> 6;
  const int oc0 = (w & 1) * 32;
  const int th = w >> 1;                  // tap-pair within chunk
  const int tile = blockIdx.x;
  const int kc = blockIdx.y;
  const int tg = tile * 32 + lo;          // reduced token (A-row m)
  const int b = tg >> 8;
  const int p = tg & 255;

  f32x16 c;
  #pragma unroll
  for (int i = 0; i < 16; ++i) c[i] = 0.f;

  #pragma unroll
  for (int sp = 0; sp < 2; ++sp) {
    const int s = kc * 4 + th * 2 + sp;   // conv tap 0..63
    const int kh = s >> 3, kw = s & 7;
    const int nrow = ((p >> 4) * 8 + kh) * WIMG + (p & 15) * 8 + kw;
    const float* xr = x + ((size_t)b * NTOK + nrow) * CDIM;
    #pragma unroll
    for (int icg = 0; icg < 4; ++icg) {
      const int ic0 = icg * 16 + hi * 8;
      float4 a0 = *(const float4*)(xr + ic0);
      float4 a1 = *(const float4*)(xr + ic0 + 4);
      float v[8] = {a0.x, a0.y, a0.z, a0.w, a1.x, a1.y, a1.z, a1.w};
      bf16x8 ah, al;
      split8(v, ah, al);
      const size_t widx = ((((size_t)s * 4 + icg) * 2 + hi) * 64 + (oc0 + lo)) * 8;
      bf16x8 bh = *(const bf16x8*)(wpk_hi + widx);
      bf16x8 bl = *(const bf16x8*)(wpk_lo + widx);
      c = mfma32x16(ah, bh, c);
      c = mfma32x16(ah, bl, c);
      c = mfma32x16(al, bh, c);
    }
  }
  const int slice = kc * 2 + th;
  #pragma unroll
  for (int r = 0; r < 16; ++r) {
    const int tokr = (r & 3) + 8 * (r >> 2) + 4 * hi;   // verified C row map
    pbuf[((size_t)slice * RTOKS + tile * 32 + tokr) * 64 + oc0 + lo] = c[r];
  }
}

// ---------------- K2: reduce 32 slices + bias + LN + KV proj -> bf16 K (scaled), bf16 V^T
__global__ __launch_bounds__(64) void k2_ln_kv(const float* __restrict__ pbuf,
                                               const float* __restrict__ srb,
                                               const float* __restrict__ lng,
                                               const float* __restrict__ lnb,
                                               const float* __restrict__ kvw,
                                               u16* __restrict__ kbuf,
                                               u16* __restrict__ vbufT) {
  __shared__ float ylds[64];
  const int tg = blockIdx.x;    // 0..511 reduced token
  const int o  = threadIdx.x;   // 0..63 channel
  float y = srb[o];
  #pragma unroll 8
  for (int s = 0; s < NSLICE; ++s) y += pbuf[((size_t)s * RTOKS + tg) * 64 + o];
  const float sum   = wave_reduce_sum64(y);
  const float sumsq = wave_reduce_sum64(y * y);
  const float mu  = sum * (1.f / 64.f);
  const float var = sumsq * (1.f / 64.f) - mu * mu;
  const float rstd = rsqrtf(var + 1e-5f);
  const float yn = (y - mu) * rstd * lng[o] + lnb[o];
  ylds[o] = yn;
  __syncthreads();
  float ka = 0.f, va = 0.f;
  #pragma unroll 16
  for (int i = 0; i < 64; ++i) {
    const float yv = ylds[i];
    ka += yv * kvw[i * 128 + o];
    va += yv * kvw[i * 128 + 64 + o];
  }
  const int b = tg >> 8, pp = tg & 255;
  const int h = o >> 3, d = o & 7;
  const int bh = b * NHEAD + h;
  kbuf[((size_t)bh * NKV + pp) * HDIM + d] = f2bf(ka * KSCALE);
  vbufT[((size_t)bh * HDIM + d) * NKV + pp] = f2bf(va);
}

// ---------------- kQ: q = x @ qw via split-bf16 MFMA -> bf16 qbuf [B][H][N][8].
__global__ __launch_bounds__(256) void kQ_qproj(const float* __restrict__ x,
                                                const u16* __restrict__ qpk_hi,
                                                const u16* __restrict__ qpk_lo,
                                                u16* __restrict__ qbuf) {
  const int t = threadIdx.x;
  const int lane = t & 63;
  const int lo = lane & 31;
  const int hi = lane >> 5;
  const int w = t >> 6;
  const int oc0 = (w & 1) * 32;
  const int blk = blockIdx.x;
  const int b = blk >> 8;
  const int tok0 = ((blk & 255) * 2 + (w >> 1)) * 32;

  f32x16 c;
  #pragma unroll
  for (int i = 0; i < 16; ++i) c[i] = 0.f;

  const float* xr = x + ((size_t)b * NTOK + tok0 + lo) * CDIM;
  #pragma unroll
  for (int icg = 0; icg < 4; ++icg) {
    const int ic0 = icg * 16 + hi * 8;
    float4 a0 = *(const float4*)(xr + ic0);
    float4 a1 = *(const float4*)(xr + ic0 + 4);
    float v[8] = {a0.x, a0.y, a0.z, a0.w, a1.x, a1.y, a1.z, a1.w};
    bf16x8 ah, al;
    split8(v, ah, al);
    const size_t qidx = (((size_t)icg * 2 + hi) * 64 + (oc0 + lo)) * 8;
    bf16x8 bh = *(const bf16x8*)(qpk_hi + qidx);
    bf16x8 bl = *(const bf16x8*)(qpk_lo + qidx);
    c = mfma32x16(ah, bh, c);
    c = mfma32x16(ah, bl, c);
    c = mfma32x16(al, bh, c);
  }
  const int oc = oc0 + lo;
  const int h = oc >> 3, d = oc & 7;
  u16* qb = qbuf + (((size_t)b * NHEAD + h) * NTOK) * HDIM + d;
  #pragma unroll
  for (int r = 0; r < 16; ++r) {
    const int tok = tok0 + (r & 3) + 8 * (r >> 2) + 4 * hi;
    qb[(size_t)tok * HDIM] = f2bf(c[r]);
  }
}

// ---------------- K4 v7: frozen r4 structure + ones-row denominator.
// V_aug^T row 8 (lanes lo==8) = 1.0 -> PV mfma accumulates den into oacc[4]
// (C row 8 = reg 4, hi=0). Deletes the 512 serial VALU den adds per wave.
__global__ __launch_bounds__(256) void k4_attn_mfma(const u16* __restrict__ qbuf,
                                                    const u16* __restrict__ kbuf,
                                                    const u16* __restrict__ vbufT,
                                                    float* __restrict__ abuf) {
  const int t = threadIdx.x;
  const int lane = t & 63;
  const int w = blockIdx.x * 4 + (t >> 6);   // global wave id, 0..2047
  const int bh = w >> 7;                     // 16 (b,h) pairs, 128 waves each
  const int wi = w & 127;
  const int lo = lane & 31;
  const int hi = lane >> 5;

  bf16x8 kf[8];
  const u16* kb = kbuf + (size_t)bh * NKV * HDIM;
  #pragma unroll
  for (int c = 0; c < 8; ++c) {
    bf16x8 z = {0, 0, 0, 0, 0, 0, 0, 0};
    if (hi == 0) z = *(const bf16x8*)(kb + (c * 32 + lo) * HDIM);
    kf[c] = z;
  }

  // V_aug^T fragments: rows 0..7 = V^T, row 8 = ones (denominator), rows 9+ = 0
  const short one_bf = (short)0x3F80;
  bf16x8 vf[16];
  const u16* vb = vbufT + (size_t)bh * HDIM * NKV;
  #pragma unroll
  for (int f = 0; f < 16; ++f) {
    bf16x8 z = {0, 0, 0, 0, 0, 0, 0, 0};
    if (lo < 8) {
      z = *(const bf16x8*)(vb + lo * NKV + f * 16 + hi * 8);
    } else if (lo == 8) {
      bf16x8 o1 = {one_bf, one_bf, one_bf, one_bf, one_bf, one_bf, one_bf, one_bf};
      z = o1;
    }
    vf[f] = z;
  }

  #pragma unroll
  for (int c = 0; c < 4; ++c) {
    const int qt = (wi * 4 + c) * 32;
    bf16x8 qf = {0, 0, 0, 0, 0, 0, 0, 0};
    if (hi == 0) qf = *(const bf16x8*)(qbuf + ((size_t)bh * NTOK + qt + lo) * HDIM);

    f32x16 oacc;
    #pragma unroll
    for (int i = 0; i < 16; ++i) oacc[i] = 0.f;

    #pragma unroll
    for (int kblk = 0; kblk < 8; ++kblk) {
      f32x16 s;
      #pragma unroll
      for (int i = 0; i < 16; ++i) s[i] = 0.f;
      s = mfma32x16(kf[kblk], qf, s);   // S^T tile

      float p[16];
      #pragma unroll
      for (int r = 0; r < 16; ++r) p[r] = fexp2(s[r]);

      unsigned pk01[4], pk23[4];
      #pragma unroll
      for (int q = 0; q < 4; ++q) {
        asm("v_cvt_pk_bf16_f32 %0, %1, %2" : "=v"(pk01[q]) : "v"(p[4*q+0]), "v"(p[4*q+1]));
        asm("v_cvt_pk_bf16_f32 %0, %1, %2" : "=v"(pk23[q]) : "v"(p[4*q+2]), "v"(p[4*q+3]));
      }
      #pragma unroll
      for (int jj = 0; jj < 2; ++jj) {
        unsigned a0 = pk01[2*jj], b0 = pk01[2*jj+1];
        unsigned a1 = pk23[2*jj], b1 = pk23[2*jj+1];
        pl32swap(a0, b0);
        pl32swap(a1, b1);
        u32x4 wv; wv[0] = a0; wv[1] = a1; wv[2] = b0; wv[3] = b1;
        bf16x8 pfrag = __builtin_bit_cast(bf16x8, wv);
        oacc = mfma32x16(vf[kblk * 2 + jj], pfrag, oacc);
      }
    }

    // epilogue: O_aug^T col=query=lo; regs0-3 = d(0..3|4..7 by hi);
    // den = row 8 = reg 4 on hi=0 lanes; hand to hi=1 via partner shfl.
    float d0 = oacc[4];
    float d1 = __shfl_xor(d0, 32, 64);
    const float den = hi ? d1 : d0;
    const float r = 1.0f / den;
    float4 o;
    o.x = oacc[0] * r; o.y = oacc[1] * r; o.z = oacc[2] * r; o.w = oacc[3] * r;
    *(float4*)(abuf + ((size_t)bh * NTOK + qt + lo) * HDIM + hi * 4) = o;
  }
}

// ---------------- kP: out = O @ pw + pb via split-bf16 MFMA.
__global__ __launch_bounds__(256) void kP_proj(const float* __restrict__ abuf,
                                               const u16* __restrict__ ppk_hi,
                                               const u16* __restrict__ ppk_lo,
                                               const float* __restrict__ pb,
                                               float* __restrict__ out) {
  const int t = threadIdx.x;
  const int lane = t & 63;
  const int lo = lane & 31;
  const int hi = lane >> 5;
  const int w = t >> 6;
  const int oc0 = (w & 1) * 32;
  const int blk = blockIdx.x;
  const int b = blk >> 8;
  const int tok0 = ((blk & 255) * 2 + (w >> 1)) * 32;

  f32x16 c;
  #pragma unroll
  for (int i = 0; i < 16; ++i) c[i] = 0.f;

  #pragma unroll
  for (int f = 0; f < 4; ++f) {
    const int h = 2 * f + hi;                 // attention-output channel group = head
    const float* src = abuf + (((size_t)b * NHEAD + h) * NTOK + tok0 + lo) * HDIM;
    float4 a0 = *(const float4*)(src);
    float4 a1 = *(const float4*)(src + 4);
    float v[8] = {a0.x, a0.y, a0.z, a0.w, a1.x, a1.y, a1.z, a1.w};
    bf16x8 ah, al;
    split8(v, ah, al);
    const size_t pidx = (((size_t)f * 2 + hi) * 64 + (oc0 + lo)) * 8;
    bf16x8 bh = *(const bf16x8*)(ppk_hi + pidx);
    bf16x8 bl = *(const bf16x8*)(ppk_lo + pidx);
    c = mfma32x16(ah, bh, c);
    c = mfma32x16(ah, bl, c);
    c = mfma32x16(al, bh, c);
  }
  const float pbv = pb[oc0 + lo];
  #pragma unroll
  for (int r = 0; r < 16; ++r) {
    const int tok = tok0 + (r & 3) + 8 * (r >> 2) + 4 * hi;
    out[((size_t)b * NTOK + tok) * CDIM + oc0 + lo] = c[r] + pbv;
  }
}

extern "C" void kernel_launch(void* const* d_in, const int* in_sizes, int n_in,
                              void* d_out, int out_size, void* d_ws, size_t ws_size,
                              hipStream_t stream) {
  const float* x    = (const float*)d_in[0];
  // d_in[1], d_in[2] are H, W scalars (128, 128) — fixed by the problem
  const float* qw   = (const float*)d_in[3];
  const float* kvw  = (const float*)d_in[4];
  const float* srw  = (const float*)d_in[5];
  const float* srb  = (const float*)d_in[6];
  const float* lng  = (const float*)d_in[7];
  const float* lnb  = (const float*)d_in[8];
  const float* pw   = (const float*)d_in[9];
  const float* pb   = (const float*)d_in[10];
  float* out = (float*)d_out;
  char* base = (char*)d_ws;

  u16*   wpk_hi = (u16*)(base);               // 524288 B
  u16*   wpk_lo = (u16*)(base + 524288);      // 524288 B
  u16*   qpk_hi = (u16*)(base + 1048576);     // 8192 B
  u16*   qpk_lo = (u16*)(base + 1056768);     // 8192 B
  u16*   ppk_hi = (u16*)(base + 1064960);     // 8192 B
  u16*   ppk_lo = (u16*)(base + 1073152);     // 8192 B
  float* pbuf   = (float*)(base + 1081344);   // 32*512*64 f32 = 4194304 B
  u16*   kbuf   = (u16*)(base + 5275648);     // 65536 B
  u16*   vbufT  = (u16*)(base + 5341184);     // 65536 B
  u16*   qbuf   = (u16*)(base + 5406720);     // 4194304 B
  float* abuf   = (float*)(base + 9601024);   // 8388608 B

  k0_pack<<<1056, 256, 0, stream>>>(srw, qw, pw, wpk_hi, wpk_lo,
                                    qpk_hi, qpk_lo, ppk_hi, ppk_lo);
  kA2_conv<<<dim3(16, 16), 256, 0, stream>>>(x, wpk_hi, wpk_lo, pbuf);
  k2_ln_kv<<<512, 64, 0, stream>>>(pbuf, srb, lng, lnb, kvw, kbuf, vbufT);
  kQ_qproj<<<512, 256, 0, stream>>>(x, qpk_hi, qpk_lo, qbuf);
  k4_attn_mfma<<<512, 256, 0, stream>>>(qbuf, kbuf, vbufT, abuf);
  kP_proj<<<512, 256, 0, stream>>>(abuf, ppk_hi, ppk_lo, pb, out);
}

// Round 13
// 45.267 us; speedup vs baseline: 1.6126x; 1.0185x over previous
//
#include <hip/hip_runtime.h>
#include <math.h>

#define NB 2
#define NTOK 16384
#define CDIM 64
#define WIMG 128
#define NKV 256
#define NHEAD 8
#define HDIM 8
#define RTOKS 512   // NB*NKV reduced tokens
#define NSLICE 32   // conv partial slices (16 kchunks x 2 tap-pairs)

typedef unsigned short u16;
typedef __attribute__((ext_vector_type(8))) short bf16x8;
typedef __attribute__((ext_vector_type(4))) unsigned int u32x4;
typedef __attribute__((ext_vector_type(2))) unsigned int u32x2;
typedef __attribute__((ext_vector_type(16))) float f32x16;

// softmax scale folded with log2(e), applied to K before bf16 quantization
constexpr float KSCALE = 0.35355339059327373f * 1.4426950408889634f;

__device__ __forceinline__ u16 f2bf(float f) {   // RNE f32->bf16
  unsigned u = __builtin_bit_cast(unsigned, f);
  return (u16)((u + 0x7FFFu + ((u >> 16) & 1u)) >> 16);
}
__device__ __forceinline__ float bf2f(u16 h) {
  return __builtin_bit_cast(float, (unsigned)h << 16);
}

__device__ __forceinline__ f32x16 mfma32x16(bf16x8 a, bf16x8 b, f32x16 c) {
  return __builtin_amdgcn_mfma_f32_32x32x16_bf16(a, b, c, 0, 0, 0);
}

__device__ __forceinline__ void pl32swap(unsigned &a, unsigned &b) {
  u32x2 r = __builtin_amdgcn_permlane32_swap(a, b, false, false);
  a = r[0]; b = r[1];
}

__device__ __forceinline__ float fexp2(float x) {
  float r;
  asm("v_exp_f32 %0, %1" : "=v"(r) : "v"(x));
  return r;
}

// split 8 f32 into hi/lo bf16 fragments: v ~= hi + lo
__device__ __forceinline__ void split8(const float* v, bf16x8& hout, bf16x8& lout) {
  unsigned hw[4], lw[4];
  float hf[8], lof[8];
  #pragma unroll
  for (int q = 0; q < 4; ++q)
    asm("v_cvt_pk_bf16_f32 %0, %1, %2" : "=v"(hw[q]) : "v"(v[2*q]), "v"(v[2*q+1]));
  #pragma unroll
  for (int q = 0; q < 4; ++q) {
    hf[2*q]   = __builtin_bit_cast(float, hw[q] << 16);
    hf[2*q+1] = __builtin_bit_cast(float, hw[q] & 0xFFFF0000u);
  }
  #pragma unroll
  for (int j = 0; j < 8; ++j) lof[j] = v[j] - hf[j];
  #pragma unroll
  for (int q = 0; q < 4; ++q)
    asm("v_cvt_pk_bf16_f32 %0, %1, %2" : "=v"(lw[q]) : "v"(lof[2*q]), "v"(lof[2*q+1]));
  u32x4 H; H[0] = hw[0]; H[1] = hw[1]; H[2] = hw[2]; H[3] = hw[3];
  u32x4 L; L[0] = lw[0]; L[1] = lw[1]; L[2] = lw[2]; L[3] = lw[3];
  hout = __builtin_bit_cast(bf16x8, H);
  lout = __builtin_bit_cast(bf16x8, L);
}

__device__ __forceinline__ float wave_reduce_sum64(float v) {
  #pragma unroll
  for (int off = 32; off > 0; off >>= 1) v += __shfl_xor(v, off, 64);
  return v;
}

// ---------------- k0p: pack all weights into MFMA-B-operand bf16 hi/lo layouts.
__global__ __launch_bounds__(256) void k0_pack(const float* __restrict__ srw,
                                               const float* __restrict__ qw,
                                               const float* __restrict__ pw,
                                               u16* __restrict__ wpk_hi, u16* __restrict__ wpk_lo,
                                               u16* __restrict__ qpk_hi, u16* __restrict__ qpk_lo,
                                               u16* __restrict__ ppk_hi, u16* __restrict__ ppk_lo) {
  int idx = blockIdx.x * 256 + threadIdx.x;   // 270336 total = 1056*256
  if (idx < 262144) {
    const int j   = idx & 7;
    const int oc  = (idx >> 3) & 63;
    const int hi  = (idx >> 9) & 1;
    const int icg = (idx >> 10) & 3;
    const int s   = idx >> 12;
    const float v = srw[oc * 4096 + (icg * 16 + hi * 8 + j) * 64 + s];
    const u16 h = f2bf(v);
    wpk_hi[idx] = h;
    wpk_lo[idx] = f2bf(v - bf2f(h));
  } else if (idx < 262144 + 4096) {
    const int q = idx - 262144;
    const int j   = q & 7;
    const int o   = (q >> 3) & 63;
    const int hi  = (q >> 9) & 1;
    const int icg = q >> 10;
    const float v = qw[(icg * 16 + hi * 8 + j) * 64 + o];
    const u16 h = f2bf(v);
    qpk_hi[q] = h;
    qpk_lo[q] = f2bf(v - bf2f(h));
  } else if (idx < 262144 + 8192) {
    const int q = idx - 262144 - 4096;
    const int j  = q & 7;
    const int o  = (q >> 3) & 63;
    const int hi = (q >> 9) & 1;
    const int g  = q >> 10;
    const float v = pw[(g * 16 + hi * 8 + j) * 64 + o];
    const u16 h = f2bf(v);
    ppk_hi[q] = h;
    ppk_lo[q] = f2bf(v - bf2f(h));
  }
}

// ---------------- kA2: conv partials via split-bf16 MFMA, coalesced packed weights.
__global__ __launch_bounds__(256) void kA2_conv(const float* __restrict__ x,
                                                const u16* __restrict__ wpk_hi,
                                                const u16* __restrict__ wpk_lo,
                                                float* __restrict__ pbuf) {
  const int t = threadIdx.x;
  const int lane = t & 63;
  const int lo = lane & 31;
  const int hi = lane >> 5;
  const int w = t >> 6;
  const int oc0 = (w & 1) * 32;
  const int th = w >> 1;                  // tap-pair within chunk
  const int tile = blockIdx.x;
  const int kc = blockIdx.y;
  const int tg = tile * 32 + lo;          // reduced token (A-row m)
  const int b = tg >> 8;
  const int p = tg & 255;

  f32x16 c;
  #pragma unroll
  for (int i = 0; i < 16; ++i) c[i] = 0.f;

  #pragma unroll
  for (int sp = 0; sp < 2; ++sp) {
    const int s = kc * 4 + th * 2 + sp;   // conv tap 0..63
    const int kh = s >> 3, kw = s & 7;
    const int nrow = ((p >> 4) * 8 + kh) * WIMG + (p & 15) * 8 + kw;
    const float* xr = x + ((size_t)b * NTOK + nrow) * CDIM;
    #pragma unroll
    for (int icg = 0; icg < 4; ++icg) {
      const int ic0 = icg * 16 + hi * 8;
      float4 a0 = *(const float4*)(xr + ic0);
      float4 a1 = *(const float4*)(xr + ic0 + 4);
      float v[8] = {a0.x, a0.y, a0.z, a0.w, a1.x, a1.y, a1.z, a1.w};
      bf16x8 ah, al;
      split8(v, ah, al);
      const size_t widx = ((((size_t)s * 4 + icg) * 2 + hi) * 64 + (oc0 + lo)) * 8;
      bf16x8 bh = *(const bf16x8*)(wpk_hi + widx);
      bf16x8 bl = *(const bf16x8*)(wpk_lo + widx);
      c = mfma32x16(ah, bh, c);
      c = mfma32x16(ah, bl, c);
      c = mfma32x16(al, bh, c);
    }
  }
  const int slice = kc * 2 + th;
  #pragma unroll
  for (int r = 0; r < 16; ++r) {
    const int tokr = (r & 3) + 8 * (r >> 2) + 4 * hi;   // verified C row map
    pbuf[((size_t)slice * RTOKS + tile * 32 + tokr) * 64 + oc0 + lo] = c[r];
  }
}

// ---------------- K2: reduce 32 slices + bias + LN + KV proj -> bf16 K (scaled), bf16 V^T
__global__ __launch_bounds__(64) void k2_ln_kv(const float* __restrict__ pbuf,
                                               const float* __restrict__ srb,
                                               const float* __restrict__ lng,
                                               const float* __restrict__ lnb,
                                               const float* __restrict__ kvw,
                                               u16* __restrict__ kbuf,
                                               u16* __restrict__ vbufT) {
  __shared__ float ylds[64];
  const int tg = blockIdx.x;    // 0..511 reduced token
  const int o  = threadIdx.x;   // 0..63 channel
  float y = srb[o];
  #pragma unroll 8
  for (int s = 0; s < NSLICE; ++s) y += pbuf[((size_t)s * RTOKS + tg) * 64 + o];
  const float sum   = wave_reduce_sum64(y);
  const float sumsq = wave_reduce_sum64(y * y);
  const float mu  = sum * (1.f / 64.f);
  const float var = sumsq * (1.f / 64.f) - mu * mu;
  const float rstd = rsqrtf(var + 1e-5f);
  const float yn = (y - mu) * rstd * lng[o] + lnb[o];
  ylds[o] = yn;
  __syncthreads();
  float ka = 0.f, va = 0.f;
  #pragma unroll 16
  for (int i = 0; i < 64; ++i) {
    const float yv = ylds[i];
    ka += yv * kvw[i * 128 + o];
    va += yv * kvw[i * 128 + 64 + o];
  }
  const int b = tg >> 8, pp = tg & 255;
  const int h = o >> 3, d = o & 7;
  const int bh = b * NHEAD + h;
  kbuf[((size_t)bh * NKV + pp) * HDIM + d] = f2bf(ka * KSCALE);
  vbufT[((size_t)bh * HDIM + d) * NKV + pp] = f2bf(va);
}

// ---------------- kQ: q = x @ qw via split-bf16 MFMA -> bf16 qbuf [B][H][N][8].
__global__ __launch_bounds__(256) void kQ_qproj(const float* __restrict__ x,
                                                const u16* __restrict__ qpk_hi,
                                                const u16* __restrict__ qpk_lo,
                                                u16* __restrict__ qbuf) {
  const int t = threadIdx.x;
  const int lane = t & 63;
  const int lo = lane & 31;
  const int hi = lane >> 5;
  const int w = t >> 6;
  const int oc0 = (w & 1) * 32;
  const int blk = blockIdx.x;
  const int b = blk >> 8;
  const int tok0 = ((blk & 255) * 2 + (w >> 1)) * 32;

  f32x16 c;
  #pragma unroll
  for (int i = 0; i < 16; ++i) c[i] = 0.f;

  const float* xr = x + ((size_t)b * NTOK + tok0 + lo) * CDIM;
  #pragma unroll
  for (int icg = 0; icg < 4; ++icg) {
    const int ic0 = icg * 16 + hi * 8;
    float4 a0 = *(const float4*)(xr + ic0);
    float4 a1 = *(const float4*)(xr + ic0 + 4);
    float v[8] = {a0.x, a0.y, a0.z, a0.w, a1.x, a1.y, a1.z, a1.w};
    bf16x8 ah, al;
    split8(v, ah, al);
    const size_t qidx = (((size_t)icg * 2 + hi) * 64 + (oc0 + lo)) * 8;
    bf16x8 bh = *(const bf16x8*)(qpk_hi + qidx);
    bf16x8 bl = *(const bf16x8*)(qpk_lo + qidx);
    c = mfma32x16(ah, bh, c);
    c = mfma32x16(ah, bl, c);
    c = mfma32x16(al, bh, c);
  }
  const int oc = oc0 + lo;
  const int h = oc >> 3, d = oc & 7;
  u16* qb = qbuf + (((size_t)b * NHEAD + h) * NTOK) * HDIM + d;
  #pragma unroll
  for (int r = 0; r < 16; ++r) {
    const int tok = tok0 + (r & 3) + 8 * (r >> 2) + 4 * hi;
    qb[(size_t)tok * HDIM] = f2bf(c[r]);
  }
}

// ---------------- K4 v8: frozen r12 arithmetic, TWIN-TILE interleave for ILP.
// Two independent q-tiles (A,B) processed per pass; their mfma/exp/pack chains
// interleave to fill each other's latency bubbles. Per-tile op sequence is
// identical to r12 -> bit-identical output. kf/vf preloaded (shared read-only),
// ones-row denominator in V_aug^T row 8.
__global__ __launch_bounds__(256) void k4_attn_mfma(const u16* __restrict__ qbuf,
                                                    const u16* __restrict__ kbuf,
                                                    const u16* __restrict__ vbufT,
                                                    float* __restrict__ abuf) {
  const int t = threadIdx.x;
  const int lane = t & 63;
  const int w = blockIdx.x * 4 + (t >> 6);   // global wave id, 0..2047
  const int bh = w >> 7;                     // 16 (b,h) pairs, 128 waves each
  const int wi = w & 127;
  const int lo = lane & 31;
  const int hi = lane >> 5;

  bf16x8 kf[8];
  const u16* kb = kbuf + (size_t)bh * NKV * HDIM;
  #pragma unroll
  for (int c = 0; c < 8; ++c) {
    bf16x8 z = {0, 0, 0, 0, 0, 0, 0, 0};
    if (hi == 0) z = *(const bf16x8*)(kb + (c * 32 + lo) * HDIM);
    kf[c] = z;
  }

  // V_aug^T fragments: rows 0..7 = V^T, row 8 = ones (denominator), rows 9+ = 0
  const short one_bf = (short)0x3F80;
  bf16x8 vf[16];
  const u16* vb = vbufT + (size_t)bh * HDIM * NKV;
  #pragma unroll
  for (int f = 0; f < 16; ++f) {
    bf16x8 z = {0, 0, 0, 0, 0, 0, 0, 0};
    if (lo < 8) {
      z = *(const bf16x8*)(vb + lo * NKV + f * 16 + hi * 8);
    } else if (lo == 8) {
      bf16x8 o1 = {one_bf, one_bf, one_bf, one_bf, one_bf, one_bf, one_bf, one_bf};
      z = o1;
    }
    vf[f] = z;
  }

  #pragma unroll
  for (int cp = 0; cp < 2; ++cp) {
    const int qtA = (wi * 4 + cp * 2) * 32;
    const int qtB = qtA + 32;
    bf16x8 qfA = {0, 0, 0, 0, 0, 0, 0, 0};
    bf16x8 qfB = {0, 0, 0, 0, 0, 0, 0, 0};
    if (hi == 0) {
      qfA = *(const bf16x8*)(qbuf + ((size_t)bh * NTOK + qtA + lo) * HDIM);
      qfB = *(const bf16x8*)(qbuf + ((size_t)bh * NTOK + qtB + lo) * HDIM);
    }

    f32x16 oA, oB;
    #pragma unroll
    for (int i = 0; i < 16; ++i) { oA[i] = 0.f; oB[i] = 0.f; }

    #pragma unroll
    for (int kblk = 0; kblk < 8; ++kblk) {
      f32x16 sA, sB;
      #pragma unroll
      for (int i = 0; i < 16; ++i) { sA[i] = 0.f; sB[i] = 0.f; }
      sA = mfma32x16(kf[kblk], qfA, sA);   // S^T tiles: two independent chains
      sB = mfma32x16(kf[kblk], qfB, sB);

      #pragma unroll
      for (int r = 0; r < 16; ++r) sA[r] = fexp2(sA[r]);
      #pragma unroll
      for (int r = 0; r < 16; ++r) sB[r] = fexp2(sB[r]);

      unsigned pkA01[4], pkA23[4], pkB01[4], pkB23[4];
      #pragma unroll
      for (int q = 0; q < 4; ++q) {
        asm("v_cvt_pk_bf16_f32 %0, %1, %2" : "=v"(pkA01[q]) : "v"(sA[4*q+0]), "v"(sA[4*q+1]));
        asm("v_cvt_pk_bf16_f32 %0, %1, %2" : "=v"(pkA23[q]) : "v"(sA[4*q+2]), "v"(sA[4*q+3]));
      }
      #pragma unroll
      for (int q = 0; q < 4; ++q) {
        asm("v_cvt_pk_bf16_f32 %0, %1, %2" : "=v"(pkB01[q]) : "v"(sB[4*q+0]), "v"(sB[4*q+1]));
        asm("v_cvt_pk_bf16_f32 %0, %1, %2" : "=v"(pkB23[q]) : "v"(sB[4*q+2]), "v"(sB[4*q+3]));
      }
      #pragma unroll
      for (int jj = 0; jj < 2; ++jj) {
        unsigned a0 = pkA01[2*jj], b0 = pkA01[2*jj+1];
        unsigned a1 = pkA23[2*jj], b1 = pkA23[2*jj+1];
        pl32swap(a0, b0);
        pl32swap(a1, b1);
        u32x4 wv; wv[0] = a0; wv[1] = a1; wv[2] = b0; wv[3] = b1;
        bf16x8 pfrag = __builtin_bit_cast(bf16x8, wv);
        oA = mfma32x16(vf[kblk * 2 + jj], pfrag, oA);
      }
      #pragma unroll
      for (int jj = 0; jj < 2; ++jj) {
        unsigned a0 = pkB01[2*jj], b0 = pkB01[2*jj+1];
        unsigned a1 = pkB23[2*jj], b1 = pkB23[2*jj+1];
        pl32swap(a0, b0);
        pl32swap(a1, b1);
        u32x4 wv; wv[0] = a0; wv[1] = a1; wv[2] = b0; wv[3] = b1;
        bf16x8 pfrag = __builtin_bit_cast(bf16x8, wv);
        oB = mfma32x16(vf[kblk * 2 + jj], pfrag, oB);
      }
    }

    // epilogues: O_aug^T col=query=lo; regs0-3 = d(0..3|4..7 by hi);
    // den = row 8 = reg 4 on hi=0 lanes; hand to hi=1 via partner shfl.
    {
      float d0 = oA[4];
      float d1 = __shfl_xor(d0, 32, 64);
      const float den = hi ? d1 : d0;
      const float r = 1.0f / den;
      float4 o;
      o.x = oA[0] * r; o.y = oA[1] * r; o.z = oA[2] * r; o.w = oA[3] * r;
      *(float4*)(abuf + ((size_t)bh * NTOK + qtA + lo) * HDIM + hi * 4) = o;
    }
    {
      float d0 = oB[4];
      float d1 = __shfl_xor(d0, 32, 64);
      const float den = hi ? d1 : d0;
      const float r = 1.0f / den;
      float4 o;
      o.x = oB[0] * r; o.y = oB[1] * r; o.z = oB[2] * r; o.w = oB[3] * r;
      *(float4*)(abuf + ((size_t)bh * NTOK + qtB + lo) * HDIM + hi * 4) = o;
    }
  }
}

// ---------------- kP: out = O @ pw + pb via split-bf16 MFMA.
__global__ __launch_bounds__(256) void kP_proj(const float* __restrict__ abuf,
                                               const u16* __restrict__ ppk_hi,
                                               const u16* __restrict__ ppk_lo,
                                               const float* __restrict__ pb,
                                               float* __restrict__ out) {
  const int t = threadIdx.x;
  const int lane = t & 63;
  const int lo = lane & 31;
  const int hi = lane >> 5;
  const int w = t >> 6;
  const int oc0 = (w & 1) * 32;
  const int blk = blockIdx.x;
  const int b = blk >> 8;
  const int tok0 = ((blk & 255) * 2 + (w >> 1)) * 32;

  f32x16 c;
  #pragma unroll
  for (int i = 0; i < 16; ++i) c[i] = 0.f;

  #pragma unroll
  for (int f = 0; f < 4; ++f) {
    const int h = 2 * f + hi;                 // attention-output channel group = head
    const float* src = abuf + (((size_t)b * NHEAD + h) * NTOK + tok0 + lo) * HDIM;
    float4 a0 = *(const float4*)(src);
    float4 a1 = *(const float4*)(src + 4);
    float v[8] = {a0.x, a0.y, a0.z, a0.w, a1.x, a1.y, a1.z, a1.w};
    bf16x8 ah, al;
    split8(v, ah, al);
    const size_t pidx = (((size_t)f * 2 + hi) * 64 + (oc0 + lo)) * 8;
    bf16x8 bh = *(const bf16x8*)(ppk_hi + pidx);
    bf16x8 bl = *(const bf16x8*)(ppk_lo + pidx);
    c = mfma32x16(ah, bh, c);
    c = mfma32x16(ah, bl, c);
    c = mfma32x16(al, bh, c);
  }
  const float pbv = pb[oc0 + lo];
  #pragma unroll
  for (int r = 0; r < 16; ++r) {
    const int tok = tok0 + (r & 3) + 8 * (r >> 2) + 4 * hi;
    out[((size_t)b * NTOK + tok) * CDIM + oc0 + lo] = c[r] + pbv;
  }
}

extern "C" void kernel_launch(void* const* d_in, const int* in_sizes, int n_in,
                              void* d_out, int out_size, void* d_ws, size_t ws_size,
                              hipStream_t stream) {
  const float* x    = (const float*)d_in[0];
  // d_in[1], d_in[2] are H, W scalars (128, 128) — fixed by the problem
  const float* qw   = (const float*)d_in[3];
  const float* kvw  = (const float*)d_in[4];
  const float* srw  = (const float*)d_in[5];
  const float* srb  = (const float*)d_in[6];
  const float* lng  = (const float*)d_in[7];
  const float* lnb  = (const float*)d_in[8];
  const float* pw   = (const float*)d_in[9];
  const float* pb   = (const float*)d_in[10];
  float* out = (float*)d_out;
  char* base = (char*)d_ws;

  u16*   wpk_hi = (u16*)(base);               // 524288 B
  u16*   wpk_lo = (u16*)(base + 524288);      // 524288 B
  u16*   qpk_hi = (u16*)(base + 1048576);     // 8192 B
  u16*   qpk_lo = (u16*)(base + 1056768);     // 8192 B
  u16*   ppk_hi = (u16*)(base + 1064960);     // 8192 B
  u16*   ppk_lo = (u16*)(base + 1073152);     // 8192 B
  float* pbuf   = (float*)(base + 1081344);   // 32*512*64 f32 = 4194304 B
  u16*   kbuf   = (u16*)(base + 5275648);     // 65536 B
  u16*   vbufT  = (u16*)(base + 5341184);     // 65536 B
  u16*   qbuf   = (u16*)(base + 5406720);     // 4194304 B
  float* abuf   = (float*)(base + 9601024);   // 8388608 B

  k0_pack<<<1056, 256, 0, stream>>>(srw, qw, pw, wpk_hi, wpk_lo,
                                    qpk_hi, qpk_lo, ppk_hi, ppk_lo);
  kA2_conv<<<dim3(16, 16), 256, 0, stream>>>(x, wpk_hi, wpk_lo, pbuf);
  k2_ln_kv<<<512, 64, 0, stream>>>(pbuf, srb, lng, lnb, kvw, kbuf, vbufT);
  kQ_qproj<<<512, 256, 0, stream>>>(x, qpk_hi, qpk_lo, qbuf);
  k4_attn_mfma<<<512, 256, 0, stream>>>(qbuf, kbuf, vbufT, abuf);
  kP_proj<<<512, 256, 0, stream>>>(abuf, ppk_hi, ppk_lo, pb, out);
}